// Round 7
// baseline (3007.091 us; speedup 1.0000x reference)
//
#include <hip/hip_runtime.h>
#include <hip/hip_bf16.h>

#define NEDGE 229376
#define NTOT  8192
#define BNCONST 0.9999950000374997f   /* 1/sqrt(1+1e-5) */
#define ISQ96   0.10206207261596575f  /* 1/sqrt(96) */

__constant__ int c_NT[5]     = {2048,2048,2048,1024,1024};
__constant__ int c_OFFS[5]   = {0,2048,4096,6144,7168};
__constant__ int c_ESRC[8]   = {0,1,1,2,0,3,1,4};
__constant__ int c_EDST[8]   = {1,0,2,2,3,1,4,2};
__constant__ int c_EOFF[9]   = {0,32768,65536,98304,131072,147456,180224,196608,229376};
__constant__ int c_RELROW[8] = {0,2048,4096,6144,8192,10240,11264,13312};

static const int h_NT[5]   = {2048,2048,2048,1024,1024};
static const int h_OFFS[5] = {0,2048,4096,6144,7168};

__device__ inline float gelu_f(float x){ return 0.5f*x*(1.0f+erff(x*0.70710678118654752f)); }
__device__ inline float sigm(float x){ return 1.0f/(1.0f+expf(-x)); }
__device__ inline float wsum64(float v){
  #pragma unroll
  for (int s=32;s>0;s>>=1) v += __shfl_xor(v, s, 64);
  return v;
}
__device__ inline unsigned encf(float f){
  unsigned b = __float_as_uint(f);
  return (b & 0x80000000u) ? ~b : (b | 0x80000000u);
}
__device__ inline float decf(unsigned u){
  unsigned b = (u & 0x80000000u) ? (u & 0x7FFFFFFFu) : ~u;
  return __uint_as_float(b);
}
__device__ inline int row_type(int row){
  return (row<2048)?0:((row<4096)?1:((row<6144)?2:((row<7168)?3:4)));
}
/* reduce across the 16-lane row group (lanes ty*16..+15) */
__device__ inline float rgmax(float v){
  v = fmaxf(v, __shfl_xor(v, 1, 64));
  v = fmaxf(v, __shfl_xor(v, 2, 64));
  v = fmaxf(v, __shfl_xor(v, 4, 64));
  v = fmaxf(v, __shfl_xor(v, 8, 64));
  return v;
}
__device__ inline float rgsum(float v){
  v += __shfl_xor(v, 1, 64);
  v += __shfl_xor(v, 2, 64);
  v += __shfl_xor(v, 4, 64);
  v += __shfl_xor(v, 8, 64);
  return v;
}

/* ---------------- simple utility kernels ---------------- */

__global__ void k_mix(const float* __restrict__ a, const float* __restrict__ b,
                      float* __restrict__ c, int n, float fa, float fb){
  int i = blockIdx.x*256 + threadIdx.x;
  if (i < n) c[i] = fa*a[i] + fb*b[i];
}

__global__ void k_comb(const float* __restrict__ ai, const float* __restrict__ user,
                       float* __restrict__ cb){
  int i = blockIdx.x*256 + threadIdx.x;
  if (i >= 2048*768) return;
  int n = i / 768, c = i - n*768;
  cb[i] = (c < 384) ? ai[n*384 + c] : user[n*384 + (c-384)];
}

/* ---------------- edge preprocessing (CSR by destination) ---------------- */

__global__ void k_edge_pre(const int* __restrict__ esrc, const int* __restrict__ edst,
                           int* edg, int* esr, int* erl, int* cnt){
  int e = blockIdx.x*256 + threadIdx.x;
  if (e >= NEDGE) return;
  int r = 0;
  #pragma unroll
  for (int q=1;q<8;q++) if (e >= c_EOFF[q]) r = q;
  int dg = c_OFFS[c_EDST[r]] + edst[e];
  edg[e] = dg;
  esr[e] = c_RELROW[r] + esrc[e];
  erl[e] = r;
  atomicAdd(&cnt[dg], 1);
}

__global__ __launch_bounds__(1024) void k_scan(const int* __restrict__ cnt, int* __restrict__ off){
  __shared__ int sh[1024];
  int tid = threadIdx.x;
  int base = tid*8;
  int loc[8]; int run = 0;
  #pragma unroll
  for (int i=0;i<8;i++){ loc[i] = run; run += cnt[base+i]; }
  sh[tid] = run;
  __syncthreads();
  for (int d=1; d<1024; d<<=1){
    int v = (tid >= d) ? sh[tid-d] : 0;
    __syncthreads();
    sh[tid] += v;
    __syncthreads();
  }
  int pre = (tid==0) ? 0 : sh[tid-1];
  #pragma unroll
  for (int i=0;i<8;i++) off[base+i] = pre + loc[i];
  if (tid==1023) off[8192] = sh[1023];
}

__global__ void k_scatter(const int* __restrict__ edg, const int* __restrict__ off,
                          int* cnt2, int* csr){
  int e = blockIdx.x*256 + threadIdx.x;
  if (e >= NEDGE) return;
  int dg = edg[e];
  int pos = off[dg] + atomicAdd(&cnt2[dg], 1);
  csr[pos] = e;
}

/* ------- tiled GEMMs: 64x64 tile, 4x4 microtile, double-buffered + float4 stage ------- */

__global__ __launch_bounds__(256) void gemm_f(
    const float* __restrict__ A, int lda, const float* __restrict__ B, int ldb,
    const float* __restrict__ bias, const float* __restrict__ cs, const float* __restrict__ csh,
    float kmul, float* __restrict__ C, int ldc, int M, int N, int K, int act, int agelu)
{
  __shared__ float As[2][16][68];
  __shared__ float Bs[2][16][68];
  int tid = threadIdx.x;
  int tx = tid & 15, ty = tid >> 4;
  int am = tid >> 2, ak = (tid & 3) * 4;
  int bk = tid >> 4, bn = (tid & 15) * 4;
  int m0 = blockIdx.y * 64, n0 = blockIdx.x * 64;
  int gmA = m0 + am;
  int gnB = n0 + bn;
  int ntiles = K >> 4;
  float4 ra, rb;
  float acc[4][4] = {};

  auto fetch = [&](int kk){
    if (gmA < M){
      ra = *reinterpret_cast<const float4*>(&A[(size_t)gmA*lda + kk + ak]);
      if (agelu){ ra.x=gelu_f(ra.x); ra.y=gelu_f(ra.y); ra.z=gelu_f(ra.z); ra.w=gelu_f(ra.w); }
    } else ra = make_float4(0.f,0.f,0.f,0.f);
    if (gnB + 3 < N){
      rb = *reinterpret_cast<const float4*>(&B[(size_t)(kk + bk)*ldb + gnB]);
    } else {
      rb.x = (gnB   < N) ? B[(size_t)(kk + bk)*ldb + gnB  ] : 0.f;
      rb.y = (gnB+1 < N) ? B[(size_t)(kk + bk)*ldb + gnB+1] : 0.f;
      rb.z = (gnB+2 < N) ? B[(size_t)(kk + bk)*ldb + gnB+2] : 0.f;
      rb.w = (gnB+3 < N) ? B[(size_t)(kk + bk)*ldb + gnB+3] : 0.f;
    }
  };
  auto stage = [&](int b){
    As[b][ak  ][am] = ra.x;
    As[b][ak+1][am] = ra.y;
    As[b][ak+2][am] = ra.z;
    As[b][ak+3][am] = ra.w;
    *reinterpret_cast<float4*>(&Bs[b][bk][bn]) = rb;
  };

  fetch(0);
  stage(0);
  __syncthreads();
  for (int t = 0; t < ntiles; t++){
    int cur = t & 1;
    if (t + 1 < ntiles) fetch((t+1) << 4);
    #pragma unroll
    for (int k = 0; k < 16; k++) {
      float4 a4 = *reinterpret_cast<const float4*>(&As[cur][k][ty*4]);
      float4 b4 = *reinterpret_cast<const float4*>(&Bs[cur][k][tx*4]);
      float a[4] = {a4.x, a4.y, a4.z, a4.w};
      float b[4] = {b4.x, b4.y, b4.z, b4.w};
      #pragma unroll
      for (int i=0;i<4;i++)
        #pragma unroll
        for (int j=0;j<4;j++) acc[i][j] += a[i]*b[j];
    }
    if (t + 1 < ntiles) stage(cur ^ 1);
    __syncthreads();
  }
  #pragma unroll
  for (int i=0;i<4;i++){
    int gm = m0 + ty*4 + i; if (gm >= M) continue;
    #pragma unroll
    for (int j=0;j<4;j++){
      int gn = n0 + tx*4 + j; if (gn >= N) continue;
      float v = acc[i][j];
      if (bias) v += bias[gn];
      float s = kmul;
      if (cs) s *= cs[gn];
      v *= s;
      if (csh) v += csh[gn];
      if (act==1) v = fmaxf(v, 0.f);
      else if (act==2) v = gelu_f(v);
      C[(size_t)gm*ldc + gn] = v;
    }
  }
}

/* ------- big GEMM v3: 64x128 tile, 4x8 SPLIT microtile, SINGLE-buffered LDS.
   Natural VGPR ~100-120 (plain launch_bounds(256) — min-waves arg spills on
   this toolchain, R3/R4), 12.8KB LDS -> 4 blocks/CU, prefetch-into-regs
   hides global latency. LDS ratio 48B/64FLOP -> ~58% VALU cap (verified
   R5: 3388->2911 with this kernel on KQV/Wout/qkv/ZNUM sites). */
__global__ __launch_bounds__(256) void gemm128(
    const float* __restrict__ A, int lda, int sAz,
    const float* __restrict__ B, int ldb, int sBz,
    const float* __restrict__ bias, int sbz,
    float* __restrict__ C, int ldc, int sCz,
    int M, int N, int K, int act, int agelu, int tsel,
    const float* __restrict__ Bp1, const float* __restrict__ Bp2,
    const float* __restrict__ biasp1, const float* __restrict__ biasp2)
{
  __shared__ float As[16][68];
  __shared__ float Bs[16][132];
  int tid = threadIdx.x;
  int tx = tid & 15, ty = tid >> 4;       /* cols group 0-15, rows group 0-15 */
  int am = tid >> 2, ak = (tid & 3) * 4;  /* A stage: row 0-63, k 0/4/8/12 */
  int bk = tid >> 4, bn = (tid & 15) * 4; /* B stage: row 0-15, col bn & bn+64 */

  /* XCD-chunked bijective swizzle of the xy-plane block id (m204 formula) */
  int nxy = gridDim.x * gridDim.y;
  int orig = blockIdx.y * gridDim.x + blockIdx.x;
  int q = nxy >> 3, r = nxy & 7;
  int xcd = orig & 7, rest = orig >> 3;
  int wg = ((xcd < r) ? xcd*(q+1) : r*(q+1) + (xcd - r)*q) + rest;
  int bx = wg % gridDim.x, by = wg / gridDim.x;
  int m0 = by * 64, n0 = bx * 128;

  int z = blockIdx.z;
  const float* Ab = A + (size_t)z * sAz;
  const float* Bb;
  const float* bb;
  if (Bp1){
    Bb = (z == 0) ? B : ((z == 1) ? Bp1 : Bp2);
    bb = (z == 0) ? bias : ((z == 1) ? biasp1 : biasp2);
  } else {
    Bb = B + (size_t)z * sBz;
    bb = bias ? (bias + (size_t)z * sbz) : nullptr;
  }
  float* Cb = C + (size_t)z * sCz;
  if (tsel){
    int t = row_type(m0);
    Bb = B + (size_t)t * sBz;
    bb = bias ? (bias + (size_t)t * sbz) : nullptr;
  }
  int gmA = m0 + am, gnB = n0 + bn;
  int ntiles = K >> 4;
  float4 ra, rb0, rb1;
  float acc[4][8] = {};

  auto fetch = [&](int kk){
    if (gmA < M){
      ra = *reinterpret_cast<const float4*>(&Ab[(size_t)gmA*lda + kk + ak]);
      if (agelu){
        ra.x=gelu_f(ra.x); ra.y=gelu_f(ra.y); ra.z=gelu_f(ra.z); ra.w=gelu_f(ra.w);
      }
    } else {
      ra = make_float4(0.f,0.f,0.f,0.f);
    }
    if (gnB + 67 < N){
      rb0 = *reinterpret_cast<const float4*>(&Bb[(size_t)(kk + bk)*ldb + gnB]);
      rb1 = *reinterpret_cast<const float4*>(&Bb[(size_t)(kk + bk)*ldb + gnB + 64]);
    } else {
      const float* bp = &Bb[(size_t)(kk + bk)*ldb];
      rb0.x = (gnB    < N) ? bp[gnB   ] : 0.f;
      rb0.y = (gnB+1  < N) ? bp[gnB+ 1] : 0.f;
      rb0.z = (gnB+2  < N) ? bp[gnB+ 2] : 0.f;
      rb0.w = (gnB+3  < N) ? bp[gnB+ 3] : 0.f;
      rb1.x = (gnB+64 < N) ? bp[gnB+64] : 0.f;
      rb1.y = (gnB+65 < N) ? bp[gnB+65] : 0.f;
      rb1.z = (gnB+66 < N) ? bp[gnB+66] : 0.f;
      rb1.w = (gnB+67 < N) ? bp[gnB+67] : 0.f;
    }
  };
  auto stage = [&](){
    As[ak  ][am] = ra.x;
    As[ak+1][am] = ra.y;
    As[ak+2][am] = ra.z;
    As[ak+3][am] = ra.w;
    *reinterpret_cast<float4*>(&Bs[bk][bn     ]) = rb0;
    *reinterpret_cast<float4*>(&Bs[bk][bn + 64]) = rb1;
  };

  fetch(0);
  for (int t = 0; t < ntiles; t++){
    if (t > 0) __syncthreads();   /* previous tile's reads complete */
    stage();
    __syncthreads();              /* staged data visible */
    if (t + 1 < ntiles) fetch((t+1) << 4);  /* loads in flight under compute */
    #pragma unroll
    for (int k = 0; k < 16; k++) {
      float4 a4 = *reinterpret_cast<const float4*>(&As[k][ty*4]);
      float4 b0 = *reinterpret_cast<const float4*>(&Bs[k][tx*4]);
      float4 b1 = *reinterpret_cast<const float4*>(&Bs[k][64 + tx*4]);
      float a[4] = {a4.x,a4.y,a4.z,a4.w};
      float b[8] = {b0.x,b0.y,b0.z,b0.w,b1.x,b1.y,b1.z,b1.w};
      #pragma unroll
      for (int i=0;i<4;i++)
        #pragma unroll
        for (int j=0;j<8;j++) acc[i][j] += a[i]*b[j];
    }
  }

  bool fullN = (n0 + 127 < N);
  int cb0 = n0 + tx*4, cb1 = n0 + 64 + tx*4;
  #pragma unroll
  for (int i=0;i<4;i++){
    int gm = m0 + ty*4 + i;
    if (gm >= M) continue;
    float v[8];
    #pragma unroll
    for (int jh=0; jh<2; jh++){
      #pragma unroll
      for (int j=0;j<4;j++){
        float x = acc[i][jh*4+j];
        int gn = (jh ? cb1 : cb0) + j;
        if (bb && gn < N) x += bb[gn];
        if (act==1) x = fmaxf(x, 0.f);
        else if (act==2) x = gelu_f(x);
        v[jh*4+j] = x;
      }
    }
    if (fullN){
      *reinterpret_cast<float4*>(&Cb[(size_t)gm*ldc + cb0]) = make_float4(v[0],v[1],v[2],v[3]);
      *reinterpret_cast<float4*>(&Cb[(size_t)gm*ldc + cb1]) = make_float4(v[4],v[5],v[6],v[7]);
    } else {
      #pragma unroll
      for (int jh=0; jh<2; jh++){
        #pragma unroll
        for (int j=0;j<4;j++){
          int gn = (jh ? cb1 : cb0) + j;
          if (gn < N) Cb[(size_t)gm*ldc + gn] = v[jh*4+j];
        }
      }
    }
  }
}

/* batched HGT relation projection as GEMM: z = (r*4+h)*2 + w */
__global__ __launch_bounds__(256) void gemm_rel(
    const float* __restrict__ KQV_, const float* __restrict__ krel_l,
    const float* __restrict__ vrel_l, float* __restrict__ KE_, float* __restrict__ VE_)
{
  int z = blockIdx.z;
  int w = z & 1, h = (z >> 1) & 3, r = z >> 3;
  int s = c_ESRC[r];
  int Ns = c_NT[s];
  int m0 = blockIdx.y * 64;
  if (m0 >= Ns) return;
  int n0 = blockIdx.x * 64;
  const float* A = KQV_ + (size_t)c_OFFS[s]*1152 + (w ? 768 : 0) + h*96;
  const float* B = (w ? vrel_l : krel_l) + (size_t)(r*4 + h)*9216;
  float* C = (w ? VE_ : KE_) + (size_t)c_RELROW[r]*384 + h*96;

  __shared__ float As[2][16][68];
  __shared__ float Bs[2][16][68];
  int tid = threadIdx.x;
  int tx = tid & 15, ty = tid >> 4;
  int am = tid >> 2, ak = (tid & 3) * 4;
  int bk = tid >> 4, bn = (tid & 15) * 4;
  int gmA = m0 + am;
  int gnB = n0 + bn;
  float4 ra, rb;
  float acc[4][4] = {};

  auto fetch = [&](int kk){
    ra = (gmA < Ns) ? *reinterpret_cast<const float4*>(&A[(size_t)gmA*1152 + kk + ak])
                    : make_float4(0.f,0.f,0.f,0.f);
    if (gnB + 3 < 96){
      rb = *reinterpret_cast<const float4*>(&B[(size_t)(kk + bk)*96 + gnB]);
    } else {
      rb.x = (gnB   < 96) ? B[(size_t)(kk + bk)*96 + gnB  ] : 0.f;
      rb.y = (gnB+1 < 96) ? B[(size_t)(kk + bk)*96 + gnB+1] : 0.f;
      rb.z = (gnB+2 < 96) ? B[(size_t)(kk + bk)*96 + gnB+2] : 0.f;
      rb.w = (gnB+3 < 96) ? B[(size_t)(kk + bk)*96 + gnB+3] : 0.f;
    }
  };
  auto stage = [&](int b){
    As[b][ak  ][am] = ra.x;
    As[b][ak+1][am] = ra.y;
    As[b][ak+2][am] = ra.z;
    As[b][ak+3][am] = ra.w;
    *reinterpret_cast<float4*>(&Bs[b][bk][bn]) = rb;
  };

  fetch(0);
  stage(0);
  __syncthreads();
  for (int t = 0; t < 6; t++){
    int cur = t & 1;
    if (t + 1 < 6) fetch((t+1) << 4);
    #pragma unroll
    for (int k = 0; k < 16; k++) {
      float4 a4 = *reinterpret_cast<const float4*>(&As[cur][k][ty*4]);
      float4 b4 = *reinterpret_cast<const float4*>(&Bs[cur][k][tx*4]);
      float a[4] = {a4.x, a4.y, a4.z, a4.w};
      float b[4] = {b4.x, b4.y, b4.z, b4.w};
      #pragma unroll
      for (int i=0;i<4;i++)
        #pragma unroll
        for (int j=0;j<4;j++) acc[i][j] += a[i]*b[j];
    }
    if (t + 1 < 6) stage(cur ^ 1);
    __syncthreads();
  }
  #pragma unroll
  for (int i=0;i<4;i++){
    int gm = m0 + ty*4 + i; if (gm >= Ns) continue;
    #pragma unroll
    for (int j=0;j<4;j++){
      int gn = n0 + tx*4 + j; if (gn >= 96) continue;
      C[(size_t)gm*384 + gn] = acc[i][j];
    }
  }
}

// C[m,n] += sum_l A[l,m]*B[l,n], head-batched + L-split (atomic accumulate).
__global__ __launch_bounds__(256) void gemm_atb_ks(
    const float* __restrict__ A0, int lda, const float* __restrict__ B0, int ldb,
    float* __restrict__ C0, int ldc, int M, int N, int L,
    int hsA, int hsB, int hsC, int nch)
{
  __shared__ float As[2][16][68];
  __shared__ float Bs[2][16][68];
  int h = blockIdx.z / nch, c = blockIdx.z % nch;
  const float* A = A0 + (size_t)h*hsA;
  const float* B = B0 + (size_t)h*hsB;
  float* C = C0 + (size_t)h*hsC;
  int l0 = c*256;
  int tid = threadIdx.x;
  int tx = tid & 15, ty = tid >> 4;
  int sl = tid >> 4, sq = (tid & 15) * 4;
  int m0 = blockIdx.y * 64, n0 = blockIdx.x * 64;
  int gmA = m0 + sq, gnB = n0 + sq;
  int ntiles = 16;
  float4 ra, rb;
  float acc[4][4] = {};

  auto fetch = [&](int ll){
    if (gmA + 3 < M){
      ra = *reinterpret_cast<const float4*>(&A[(size_t)(ll + sl)*lda + gmA]);
    } else {
      ra.x = (gmA   < M) ? A[(size_t)(ll + sl)*lda + gmA  ] : 0.f;
      ra.y = (gmA+1 < M) ? A[(size_t)(ll + sl)*lda + gmA+1] : 0.f;
      ra.z = (gmA+2 < M) ? A[(size_t)(ll + sl)*lda + gmA+2] : 0.f;
      ra.w = (gmA+3 < M) ? A[(size_t)(ll + sl)*lda + gmA+3] : 0.f;
    }
    if (gnB + 3 < N){
      rb = *reinterpret_cast<const float4*>(&B[(size_t)(ll + sl)*ldb + gnB]);
    } else {
      rb.x = (gnB   < N) ? B[(size_t)(ll + sl)*ldb + gnB  ] : 0.f;
      rb.y = (gnB+1 < N) ? B[(size_t)(ll + sl)*ldb + gnB+1] : 0.f;
      rb.z = (gnB+2 < N) ? B[(size_t)(ll + sl)*ldb + gnB+2] : 0.f;
      rb.w = (gnB+3 < N) ? B[(size_t)(ll + sl)*ldb + gnB+3] : 0.f;
    }
  };
  auto stage = [&](int b){
    *reinterpret_cast<float4*>(&As[b][sl][sq]) = ra;
    *reinterpret_cast<float4*>(&Bs[b][sl][sq]) = rb;
  };

  fetch(l0);
  stage(0);
  __syncthreads();
  for (int t = 0; t < ntiles; t++){
    int cur = t & 1;
    if (t + 1 < ntiles) fetch(l0 + ((t+1) << 4));
    #pragma unroll
    for (int l = 0; l < 16; l++) {
      float4 a4 = *reinterpret_cast<const float4*>(&As[cur][l][ty*4]);
      float4 b4 = *reinterpret_cast<const float4*>(&Bs[cur][l][tx*4]);
      float a[4] = {a4.x, a4.y, a4.z, a4.w};
      float b[4] = {b4.x, b4.y, b4.z, b4.w};
      #pragma unroll
      for (int i=0;i<4;i++)
        #pragma unroll
        for (int j=0;j<4;j++) acc[i][j] += a[i]*b[j];
    }
    if (t + 1 < ntiles) stage(cur ^ 1);
    __syncthreads();
  }
  #pragma unroll
  for (int i=0;i<4;i++){
    int gm = m0 + ty*4 + i; if (gm >= M) continue;
    #pragma unroll
    for (int j=0;j<4;j++){
      int gn = n0 + tx*4 + j; if (gn >= N) continue;
      atomicAdd(&C[(size_t)gm*ldc + gn], acc[i][j]);
    }
  }
}

/* ------- flash attention v2: q-tile 64, kv-tile 64, 4x4 QK microtile --------
   R7: fa was LDS-BW-bound (VALUBusy 45% == the 0.83 FLOP/LDS-byte cap of the
   4x2 microtile). Raise the ratio to 1.08 F/B (cap ~54%):
   - QK^T 4x4 microtile over a 64-kv tile (16B Q + 16B K per k for 32 FLOP)
   - K and P share ONE LDS buffer (K dead after S; P overwrites after barrier)
   - V staged in two 32-kv halves reusing one 12.8KB buffer
   LDS = 26112(Q) + 26112(K|P) + 12800(V) = 65024 <= 64KB. 6 barriers/64kv
   (was 4) but each compute phase is 2x bigger.
   grid (nq/64, 4 heads, nkv/512); MQKV row*1152: Q[0..383] K[384..767] V[768..1151] */
__global__ __launch_bounds__(256) void fa_kernel(
    const float* __restrict__ MQ, int nq, float* __restrict__ OP, float* __restrict__ ML)
{
  __shared__ float Qs[96][68];    /* [d][q-row] */
  __shared__ float KP[96][68];    /* K: [d][kv 0..63] ; later P: [q 0..63][kv 0..63] */
  __shared__ float Vs[32][100];   /* half kv-tile: [kv][d] */
  int tid = threadIdx.x;
  int tx = tid & 15, ty = tid >> 4;
  int q0 = blockIdx.x * 64;
  int h = blockIdx.y;
  int z = blockIdx.z, nch = gridDim.z;
  int kvbase = z * 512;

  /* stage Q tile [d][r] */
  #pragma unroll
  for (int i = 0; i < 6; i++){
    int e = tid + i*256;
    int r = e & 63, kq = (e >> 6) * 4;
    float4 f = *reinterpret_cast<const float4*>(&MQ[(size_t)(q0+r)*1152 + h*96 + kq]);
    Qs[kq  ][r] = f.x;
    Qs[kq+1][r] = f.y;
    Qs[kq+2][r] = f.z;
    Qs[kq+3][r] = f.w;
  }

  float m_i[4], l_i[4], acc[4][6];
  #pragma unroll
  for (int i=0;i<4;i++){
    m_i[i] = -3.0e38f; l_i[i] = 0.f;
    #pragma unroll
    for (int c=0;c<6;c++) acc[i][c] = 0.f;
  }
  int c0 = tx*6;

  for (int t = 0; t < 8; t++){
    int kv0 = kvbase + t*64;
    __syncthreads();   /* prev tile's P/V reads done; Q staged (t==0) */

    /* stage K tile [d][n] (64 kv) and V half0 [n][d] (kv 0..31) */
    #pragma unroll
    for (int i = 0; i < 6; i++){
      int e = tid + i*256;
      int n = e & 63, kq = (e >> 6) * 4;
      float4 f = *reinterpret_cast<const float4*>(&MQ[(size_t)(kv0+n)*1152 + 384 + h*96 + kq]);
      KP[kq  ][n] = f.x;
      KP[kq+1][n] = f.y;
      KP[kq+2][n] = f.z;
      KP[kq+3][n] = f.w;
    }
    #pragma unroll
    for (int i = 0; i < 3; i++){
      int e = tid + i*256;
      int nv = e / 24, cq = (e - nv*24) * 4;
      float4 g = *reinterpret_cast<const float4*>(&MQ[(size_t)(kv0+nv)*1152 + 768 + h*96 + cq]);
      *reinterpret_cast<float4*>(&Vs[nv][cq]) = g;
    }
    __syncthreads();

    /* S = Q @ K^T (64x64), thread: rows ty*4..+3, kv cols tx*4..+3 */
    float s[4][4] = {};
    #pragma unroll 8
    for (int k = 0; k < 96; k++){
      float4 a4 = *reinterpret_cast<const float4*>(&Qs[k][ty*4]);
      float4 b4 = *reinterpret_cast<const float4*>(&KP[k][tx*4]);
      float a[4] = {a4.x, a4.y, a4.z, a4.w};
      float b[4] = {b4.x, b4.y, b4.z, b4.w};
      #pragma unroll
      for (int i=0;i<4;i++)
        #pragma unroll
        for (int j=0;j<4;j++) s[i][j] += a[i]*b[j];
    }
    /* online softmax per row; p kept in regs until K reads complete */
    float p[4][4];
    #pragma unroll
    for (int i=0;i<4;i++){
      float v0 = s[i][0]*ISQ96, v1 = s[i][1]*ISQ96;
      float v2 = s[i][2]*ISQ96, v3 = s[i][3]*ISQ96;
      float rm = rgmax(fmaxf(fmaxf(v0, v1), fmaxf(v2, v3)));
      float mn = fmaxf(m_i[i], rm);
      float alpha = expf(m_i[i] - mn);
      p[i][0] = expf(v0 - mn); p[i][1] = expf(v1 - mn);
      p[i][2] = expf(v2 - mn); p[i][3] = expf(v3 - mn);
      float rs = rgsum(p[i][0] + p[i][1] + p[i][2] + p[i][3]);
      l_i[i] = l_i[i]*alpha + rs;
      m_i[i] = mn;
      #pragma unroll
      for (int c=0;c<6;c++) acc[i][c] *= alpha;
    }
    __syncthreads();   /* all K reads finished */
    /* write P over K's buffer: rows = q, cols = kv */
    #pragma unroll
    for (int i=0;i<4;i++)
      *reinterpret_cast<float4*>(&KP[ty*4+i][tx*4]) =
          make_float4(p[i][0], p[i][1], p[i][2], p[i][3]);
    __syncthreads();   /* P visible */

    /* O += P @ V, half 0 (kv 0..31) */
    for (int kv = 0; kv < 32; kv++){
      float2 v01 = *reinterpret_cast<const float2*>(&Vs[kv][c0]);
      float2 v23 = *reinterpret_cast<const float2*>(&Vs[kv][c0+2]);
      float2 v45 = *reinterpret_cast<const float2*>(&Vs[kv][c0+4]);
      #pragma unroll
      for (int i=0;i<4;i++){
        float pv = KP[ty*4+i][kv];
        acc[i][0] += pv*v01.x; acc[i][1] += pv*v01.y;
        acc[i][2] += pv*v23.x; acc[i][3] += pv*v23.y;
        acc[i][4] += pv*v45.x; acc[i][5] += pv*v45.y;
      }
    }
    __syncthreads();   /* V half0 reads done */
    /* stage V half1 (kv 32..63) */
    #pragma unroll
    for (int i = 0; i < 3; i++){
      int e = tid + i*256;
      int nv = e / 24, cq = (e - nv*24) * 4;
      float4 g = *reinterpret_cast<const float4*>(&MQ[(size_t)(kv0+32+nv)*1152 + 768 + h*96 + cq]);
      *reinterpret_cast<float4*>(&Vs[nv][cq]) = g;
    }
    __syncthreads();
    /* O += P @ V, half 1 (kv 32..63) */
    for (int kv = 0; kv < 32; kv++){
      float2 v01 = *reinterpret_cast<const float2*>(&Vs[kv][c0]);
      float2 v23 = *reinterpret_cast<const float2*>(&Vs[kv][c0+2]);
      float2 v45 = *reinterpret_cast<const float2*>(&Vs[kv][c0+4]);
      #pragma unroll
      for (int i=0;i<4;i++){
        float pv = KP[ty*4+i][32+kv];
        acc[i][0] += pv*v01.x; acc[i][1] += pv*v01.y;
        acc[i][2] += pv*v23.x; acc[i][3] += pv*v23.y;
        acc[i][4] += pv*v45.x; acc[i][5] += pv*v45.y;
      }
    }
  }

  /* write unnormalized partials */
  size_t base = ((size_t)(h*nch + z)*nq + q0);
  #pragma unroll
  for (int i=0;i<4;i++){
    size_t row = base + ty*4 + i;
    #pragma unroll
    for (int c=0;c<6;c++) OP[row*96 + c0 + c] = acc[i][c];
    if (tx == 0){
      ML[row*2  ] = m_i[i];
      ML[row*2+1] = l_i[i];
    }
  }
}

__global__ void k_famerge(const float* __restrict__ OP, const float* __restrict__ ML,
                          float* __restrict__ AO_, int nq, int nch){
  int e = blockIdx.x*256 + threadIdx.x;
  int total = 4*nq*96;
  if (e >= total) return;
  int c = e % 96;
  int q = (e / 96) % nq;
  int h = e / (96*nq);
  float M = -3.0e38f;
  for (int z = 0; z < nch; z++)
    M = fmaxf(M, ML[((size_t)(h*nch+z)*nq + q)*2]);
  float L = 0.f, O = 0.f;
  for (int z = 0; z < nch; z++){
    size_t row = (size_t)(h*nch+z)*nq + q;
    float w = expf(ML[row*2] - M);
    L += ML[row*2+1]*w;
    O += OP[row*96 + c]*w;
  }
  AO_[(size_t)q*384 + h*96 + c] = O / L;
}

/* ---------------- conv1d as im2col + GEMM ---------------- */
/* imcol[p][ic*3+j] = in[p-1+j][ic] (0-pad); matches per-ic j-inner accumulation order */
__global__ void k_im2col(const float* __restrict__ in, float* __restrict__ imc){
  int e = blockIdx.x*256 + threadIdx.x;
  if (e >= 2048*1152) return;
  int p = e / 1152, k = e - p*1152;
  int ic = k / 3, j = k - ic*3;
  int gp = p - 1 + j;
  imc[e] = (gp >= 0 && gp < 2048) ? in[(size_t)gp*384 + ic] : 0.f;
}
/* WT[k][oc] = W[oc][k], K = 1152 */
__global__ void k_wtr(const float* __restrict__ W, float* __restrict__ WT, int OC){
  int e = blockIdx.x*256 + threadIdx.x;
  if (e >= OC*1152) return;
  int oc = e / 1152, k = e - oc*1152;
  WT[(size_t)k*OC + oc] = W[e];
}

/* ---------------- edge attention ---------------- */

__global__ __launch_bounds__(256) void k_escore(
    const float* __restrict__ KQV_, const float* __restrict__ KE_,
    const int* __restrict__ edg, const int* __restrict__ esr, const int* __restrict__ erl,
    const float* __restrict__ prel_l, float* __restrict__ EA)
{
  int e = blockIdx.x*4 + (threadIdx.x>>6);
  if (e >= NEDGE) return;
  int lane = threadIdx.x & 63;
  int h = lane >> 4, j = lane & 15;
  int dg = edg[e], sr = esr[e], r = erl[e];
  const float* q  = KQV_ + (size_t)dg*1152 + 384 + h*96;
  const float* ke = KE_  + (size_t)sr*384 + h*96;
  float p = 0.f;
  #pragma unroll
  for (int t=0;t<6;t++){ int d = j + t*16; p += q[d]*ke[d]; }
  p += __shfl_xor(p, 1, 64);
  p += __shfl_xor(p, 2, 64);
  p += __shfl_xor(p, 4, 64);
  p += __shfl_xor(p, 8, 64);
  if (j == 0) EA[(size_t)e*4 + h] = p * prel_l[r*4+h] * ISQ96;
}

__global__ void k_segmax(const float* __restrict__ EA, const int* __restrict__ edg,
                         unsigned* __restrict__ EMX){
  int i = blockIdx.x*256 + threadIdx.x;
  if (i >= NEDGE*4) return;
  int e = i >> 2, h = i & 3;
  atomicMax(&EMX[edg[e]*4 + h], encf(EA[i]));
}

__global__ void k_expsum(float* __restrict__ EA, const int* __restrict__ edg,
                         const unsigned* __restrict__ EMX, float* __restrict__ EDEN){
  int i = blockIdx.x*256 + threadIdx.x;
  if (i >= NEDGE*4) return;
  int e = i >> 2, h = i & 3;
  int dg = edg[e];
  float m = decf(EMX[dg*4 + h]);
  float ex = expf(EA[i] - m);
  EA[i] = ex;
  atomicAdd(&EDEN[dg*4 + h], ex);
}

__global__ __launch_bounds__(128) void k_agg(
    const float* __restrict__ EA, const float* __restrict__ VE_,
    const float* __restrict__ EDEN, const int* __restrict__ csr,
    const int* __restrict__ off, const int* __restrict__ esr, float* __restrict__ AGG)
{
  int node = blockIdx.x, tid = threadIdx.x;
  int b = off[node], e1 = off[node+1];
  int d0 = tid, d1 = tid+128, d2 = tid+256;
  int h0 = d0/96, h1 = d1/96, h2 = d2/96;
  float a0=0.f, a1=0.f, a2=0.f;
  if (e1 > b){
    float i0 = 1.0f/EDEN[node*4+h0];
    float i1 = 1.0f/EDEN[node*4+h1];
    float i2 = 1.0f/EDEN[node*4+h2];
    for (int p=b; p<e1; p++){
      int e = csr[p];
      const float* ve = VE_ + (size_t)esr[e]*384;
      const float* ea = EA + (size_t)e*4;
      a0 += ea[h0]*i0*ve[d0];
      a1 += ea[h1]*i1*ve[d1];
      a2 += ea[h2]*i2*ve[d2];
    }
  }
  AGG[(size_t)node*384 + d0] = a0;
  AGG[(size_t)node*384 + d1] = a1;
  AGG[(size_t)node*384 + d2] = a2;
}

/* ---------------- row-wise norm kernels ---------------- */

__global__ __launch_bounds__(128) void k_gateln(
    const float* __restrict__ O, float* __restrict__ X,
    const float* __restrict__ skip_l, const float* __restrict__ lng, const float* __restrict__ lnb)
{
  __shared__ float red[2];
  int row = blockIdx.x, tid = threadIdx.x;
  int t = row_type(row);
  float gt = sigm(skip_l[t]);
  const float* o = O + (size_t)row*384;
  float* x = X + (size_t)row*384;
  float v0 = gelu_f(gt*o[tid]     + (1.f-gt)*x[tid]);
  float v1 = gelu_f(gt*o[tid+128] + (1.f-gt)*x[tid+128]);
  float v2 = gelu_f(gt*o[tid+256] + (1.f-gt)*x[tid+256]);
  int lane = tid & 63, wid = tid >> 6;
  float s = wsum64(v0+v1+v2);
  if (lane==0) red[wid] = s;
  __syncthreads();
  float mean = (red[0]+red[1]) * (1.0f/384.0f);
  __syncthreads();
  float d0=v0-mean, d1=v1-mean, d2=v2-mean;
  float q = wsum64(d0*d0+d1*d1+d2*d2);
  if (lane==0) red[wid] = q;
  __syncthreads();
  float var = (red[0]+red[1]) * (1.0f/384.0f);
  float rs = 1.0f/sqrtf(var + 1e-5f);
  const float* g = lng + (size_t)t*384;
  const float* b = lnb + (size_t)t*384;
  x[tid]     = d0*rs*g[tid]     + b[tid];
  x[tid+128] = d1*rs*g[tid+128] + b[tid+128];
  x[tid+256] = d2*rs*g[tid+256] + b[tid+256];
}

__global__ __launch_bounds__(128) void k_lnrow(
    const float* __restrict__ X, float* __restrict__ Y,
    const float* __restrict__ g, const float* __restrict__ b, int act)
{
  __shared__ float red[2];
  int row = blockIdx.x, tid = threadIdx.x;
  const float* x = X + (size_t)row*384;
  float* y = Y + (size_t)row*384;
  float v0 = x[tid], v1 = x[tid+128], v2 = x[tid+256];
  int lane = tid & 63, wid = tid >> 6;
  float s = wsum64(v0+v1+v2);
  if (lane==0) red[wid] = s;
  __syncthreads();
  float mean = (red[0]+red[1]) * (1.0f/384.0f);
  __syncthreads();
  float d0=v0-mean, d1=v1-mean, d2=v2-mean;
  float q = wsum64(d0*d0+d1*d1+d2*d2);
  if (lane==0) red[wid] = q;
  __syncthreads();
  float var = (red[0]+red[1]) * (1.0f/384.0f);
  float rs = 1.0f/sqrtf(var + 1e-5f);
  float u0 = d0*rs*g[tid]     + b[tid];
  float u1 = d1*rs*g[tid+128] + b[tid+128];
  float u2 = d2*rs*g[tid+256] + b[tid+256];
  if (act==1){ u0=fmaxf(u0,0.f); u1=fmaxf(u1,0.f); u2=fmaxf(u2,0.f); }
  else       { u0=gelu_f(u0); u1=gelu_f(u1); u2=gelu_f(u2); }
  y[tid] = u0; y[tid+128] = u1; y[tid+256] = u2;
}

/* ---------------- reductions / misc ---------------- */

__global__ __launch_bounds__(256) void k_sumsq(const float* __restrict__ x, int n, float* out){
  __shared__ float red[4];
  float s = 0.f;
  for (int i = blockIdx.x*256 + threadIdx.x; i < n; i += gridDim.x*256){ float v=x[i]; s += v*v; }
  s = wsum64(s);
  int lane = threadIdx.x & 63, wid = threadIdx.x >> 6;
  if (lane==0) red[wid] = s;
  __syncthreads();
  if (threadIdx.x==0) atomicAdd(out, red[0]+red[1]+red[2]+red[3]);
}

__global__ void k_colsum(const float* __restrict__ A, int R, int C, float scale,
                         float* __restrict__ out){
  int col = blockIdx.x*256 + threadIdx.x;
  if (col >= C) return;
  int nchunk = gridDim.y;
  int chunk = (R + nchunk - 1)/nchunk;
  int r0 = blockIdx.y*chunk, r1 = min(R, r0+chunk);
  float s = 0.f;
  for (int r=r0; r<r1; r++) s += A[(size_t)r*C + col];
  atomicAdd(&out[col], s*scale);
}

__global__ __launch_bounds__(256) void k_dnm(const float* __restrict__ QB,
    const float* __restrict__ KSUM, const float* __restrict__ sqsk, float* __restrict__ DNM){
  int wv = blockIdx.x*4 + (threadIdx.x>>6);
  int n = wv >> 2, h = wv & 3;
  int lane = threadIdx.x & 63;
  const float* q = QB + (size_t)n*1536 + h*384;
  const float* ks = KSUM + h*384;
  float p = 0.f;
  #pragma unroll
  for (int d=lane; d<384; d+=64) p += q[d]*ks[d];
  p = wsum64(p);
  if (lane==0) DNM[n*4+h] = p * (1.0f/sqrtf(sqsk[0]*sqsk[1])) + 2048.0f;
}

__global__ void k_zcomb(const float* __restrict__ ZN, const float* __restrict__ VB_,
                        const float* __restrict__ DNM_, const float* __restrict__ sqsk,
                        float* __restrict__ XG_,
                        const float* __restrict__ bng, const float* __restrict__ bnb){
  int i = blockIdx.x*256 + threadIdx.x;
  if (i >= 2048*384) return;
  int n = i / 384, c = i - n*384;
  float inv_s = 1.0f/sqrtf(sqsk[0]*sqsk[1]);
  float zm = 0.f;
  #pragma unroll
  for (int h=0;h<4;h++){
    float num = ZN[(size_t)n*1536 + h*384 + c]*inv_s + 2048.0f*VB_[(size_t)n*1536 + h*384 + c];
    zm += num / DNM_[n*4+h];
  }
  zm *= 0.25f;
  float y = 0.5f*zm + 0.5f*XG_[i];
  y = y * (bng[c] * BNCONST) + bnb[c];
  XG_[i] = fmaxf(y, 0.f);
}

/* ---------------- parallel small GEMV: partials + finalize ---------------- */

__global__ __launch_bounds__(256) void k_gemv_ks(
    const float* __restrict__ in, int K, const float* __restrict__ W, int ldw,
    float* __restrict__ tmp, int N)
{
  int c = blockIdx.x*64 + (threadIdx.x & 63);
  int w = threadIdx.x >> 6;
  int kch = blockIdx.y, nk = gridDim.y;
  int k0 = (int)(((long long)K * kch) / nk);
  int k1 = (int)(((long long)K * (kch+1)) / nk);
  float s = 0.f;
  if (c < N){
    for (int k = k0 + w; k < k1; k += 4)
      s += in[k] * W[(size_t)k*ldw + c];
  }
  __shared__ float red[4][64];
  red[w][threadIdx.x & 63] = s;
  __syncthreads();
  if (w == 0 && c < N){
    int l = threadIdx.x & 63;
    tmp[(size_t)kch*N + c] = red[0][l] + red[1][l] + red[2][l] + red[3][l];
  }
}

__global__ void k_gemv_fin(const float* __restrict__ tmp, int nk,
                           const float* __restrict__ b, float* __restrict__ out, int N, int act){
  int c = blockIdx.x*256 + threadIdx.x;
  if (c >= N) return;
  float v = 0.f;
  for (int i = 0; i < nk; i++) v += tmp[(size_t)i*N + c];
  v += b[c];
  if (act==1) v = fmaxf(v, 0.f);
  out[c] = v;
}

__global__ __launch_bounds__(256) void k_rowdot(const float* __restrict__ A, int lda, int K,
    const float* __restrict__ w, const float* __restrict__ b, float* __restrict__ out, int M){
  int r = blockIdx.x*4 + (threadIdx.x>>6);
  if (r >= M) return;
  int lane = threadIdx.x & 63;
  const float* a = A + (size_t)r*lda;
  float p = 0.f;
  for (int k = lane; k < K; k += 64) p += a[k]*w[k];
  p = wsum64(p);
  if (lane==0) out[r] = sigm(p + b[0]);
}

__global__ __launch_bounds__(64) void k_final(const float* __restrict__ z2,
    const float* __restrict__ w, const float* __restrict__ b, float* __restrict__ out){
  int lane = threadIdx.x;
  float p = 0.f;
  for (int k = lane; k < 192; k += 64) p += z2[k]*w[k];
  p = wsum64(p);
  if (lane==0){
    float l = p + b[0];
    out[0] = l;
    out[1] = sigm(l);
  }
}

/* ================================================================ */

extern "C" void kernel_launch(void* const* d_in, const int* in_sizes, int n_in,
                              void* d_out, int out_size, void* d_ws, size_t ws_size,
                              hipStream_t stream)
{
  const float* xin[5] = {(const float*)d_in[0], (const float*)d_in[1], (const float*)d_in[2],
                         (const float*)d_in[3], (const float*)d_in[4]};
  const float* Wkqv=(const float*)d_in[5];  const float* bkqv=(const float*)d_in[6];
  const float* Wout=(const float*)d_in[7];  const float* bout=(const float*)d_in[8];
  const float* krel=(const float*)d_in[9];  const float* vrel=(const float*)d_in[10];
  const float* prel=(const float*)d_in[11]; const float* skp =(const float*)d_in[12];
  const float* lng =(const float*)d_in[13]; const float* lnb =(const float*)d_in[14];
  const float* sp_W=(const float*)d_in[15]; const float* sp_b=(const float*)d_in[16];
  const float* sp_lng=(const float*)d_in[17]; const float* sp_lnb=(const float*)d_in[18];
  const float* fc0_W=(const float*)d_in[19]; const float* fc0_b=(const float*)d_in[20];
  const float* bn_g=(const float*)d_in[21]; const float* bn_b=(const float*)d_in[22];
  const float* tq_W=(const float*)d_in[23]; const float* tq_b=(const float*)d_in[24];
  const float* tk_W=(const float*)d_in[25]; const float* tk_b=(const float*)d_in[26];
  const float* tv_W=(const float*)d_in[27]; const float* tv_b=(const float*)d_in[28];
  const float* mWqkv=(const float*)d_in[29]; const float* mbqkv=(const float*)d_in[30];
  const float* mWo=(const float*)d_in[31];  const float* mbo=(const float*)d_in[32];
  const float* c1W=(const float*)d_in[33];  const float* c1b=(const float*)d_in[34];
  const float* c2W=(const float*)d_in[35];  const float* c2b=(const float*)d_in[36];
  const float* opW=(const float*)d_in[37];  const float* opb=(const float*)d_in[38];
  const float* as1W=(const float*)d_in[39]; const float* as1b=(const float*)d_in[40];
  const float* as2W=(const float*)d_in[41]; const float* as2b=(const float*)d_in[42];
  const float* sc1W=(const float*)d_in[43]; const float* sc1b=(const float*)d_in[44];
  const float* sc2W=(const float*)d_in[45]; const float* sc2b=(const float*)d_in[46];
  const float* cl1W=(const float*)d_in[47]; const float* cl1b=(const float*)d_in[48];
  const float* cllng=(const float*)d_in[49]; const float* cllnb=(const float*)d_in[50];
  const float* cl2W=(const float*)d_in[51]; const float* cl2b=(const float*)d_in[52];
  const float* cl3W=(const float*)d_in[53]; const float* cl3b=(const float*)d_in[54];
  const float* tpW=(const float*)d_in[55];  const float* tpb=(const float*)d_in[56];
  const int* e_src=(const int*)d_in[57];  const int* e_dst=(const int*)d_in[58];
  float* out = (float*)d_out;

  /* workspace arena */
  char* ws = (char*)d_ws;
  size_t off_b = 0;
  auto alloc = [&](size_t bytes)->char*{
    char* r = ws + off_b;
    off_b = (off_b + bytes + 255) & ~(size_t)255;
    return r;
  };
  float* X    = (float*)alloc((size_t)8192*384*4);
  float* KQV  = (float*)alloc((size_t)8192*1152*4);
  float* KE   = (float*)alloc((size_t)14336*384*4);
  float* VE   = (float*)alloc((size_t)14336*384*4);
  float* AGG  = (float*)alloc((size_t)8192*384*4);
  float* EA   = (float*)alloc((size_t)NEDGE*4*4);
  int* edg    = (int*)alloc((size_t)NEDGE*4);
  int* esr    = (int*)alloc((size_t)NEDGE*4);
  int* erl    = (int*)alloc((size_t)NEDGE*4);
  int* csr    = (int*)alloc((size_t)NEDGE*4);
  int* cnt    = (int*)alloc(8192*4);
  int* cnt2   = (int*)alloc(8192*4);
  int* coff   = (int*)alloc(8193*4);
  unsigned* EMX = (unsigned*)alloc(8192*4*4);
  float* EDEN = (float*)alloc(8192*4*4);
  float* SM   = (float*)alloc(65536);
  float* GT   = (float*)alloc(20*384*4);
  if (off_b > ws_size) return;

  float* SQSK = SM;
  float* TRAJSUM = SM + 8;
  float* DECAYSUM = SM + 392;
  float* TEMB = SM + 600;
  float* AIPOOL = SM + 984;
  float* BCTXV = SM + 1368;
  float* SDELT = SM + 1752;
  float* SDIN = SM + 2048;
  float* T1   = SM + 2816;
  float* Z1   = SM + 3200;
  float* Zb   = SM + 3584;
  float* Z2   = SM + 3968;
  float* KSUM = SM + 4224;
  float* DNM  = SM + 6144;

  float* QB = KQV;
  float* KB = KQV + (size_t)2048*1536;
  float* VB = KQV + (size_t)2*2048*1536;
  float* MQKV = KQV;
  float* AO = KQV + (size_t)2*2048*1536;
  float* ZNUM = KE;
  float* OWT = KE;
  float* OPART = KE;                       /* flash partials: <= 4*4*2048*96 */
  float* MLBUF = KE + (size_t)3200000;     /* <= 65536 floats */
  float* IMC = KE;                         /* conv im2col 2048x1152 */
  float* WT  = KE + (size_t)2400000;       /* conv weight^T <= 1152*384 */
  float* HS = VE;
  float* XG = VE + (size_t)2048*384;
  float* HM = VE + (size_t)2*2048*384;
  float* C1O = VE + (size_t)3*2048*384;
  float* TRAJ = VE + (size_t)4*2048*384;
  float* AICTX = VE + (size_t)5*2048*384;
  float* C2O = VE + (size_t)6*2048*384;
  float* TMPA = AGG;
  float* CB = AGG;
  float* PT = AGG + (size_t)2048*768;
  float* KVS = AGG + (size_t)2048*1152;

  dim3 B256(256);
  auto gemm = [&](const float* A, int lda, const float* Bw, int ldb, const float* bias,
                  const float* cs, const float* csh, float kmul,
                  float* C, int ldc, int M, int N, int K, int act, int agelu){
    dim3 g((N+63)/64, (M+63)/64);
    gemm_f<<<g, B256, 0, stream>>>(A, lda, Bw, ldb, bias, cs, csh, kmul, C, ldc, M, N, K, act, agelu);
  };
  /* plain (no cs/csh) GEMM on the 64x128 kernel */
  auto gemm_big = [&](const float* A, int lda, const float* Bw, int ldb, const float* bias,
                      float* C, int ldc, int M, int N, int K, int act, int agelu){
    dim3 g((N+127)/128, (M+63)/64);
    gemm128<<<g, B256, 0, stream>>>(A, lda, 0, Bw, ldb, 0, bias, 0,
                                    C, ldc, 0, M, N, K, act, agelu, 0,
                                    nullptr, nullptr, nullptr, nullptr);
  };
  auto gemv = [&](const float* in, int K, const float* W, int ldw, const float* b,
                  float* o, int N, int act){
    int nk = (K + 79) / 80; if (nk > 20) nk = 20; if (nk < 1) nk = 1;
    k_gemv_ks<<<dim3((N+63)/64, nk), B256, 0, stream>>>(in, K, W, ldw, GT, N);
    k_gemv_fin<<<dim3((N+255)/256), B256, 0, stream>>>(GT, nk, b, o, N, act);
  };

  /* ---- edge CSR ---- */
  hipMemsetAsync(cnt, 0, 8192*4, stream);
  hipMemsetAsync(cnt2, 0, 8192*4, stream);
  k_edge_pre<<<dim3(NEDGE/256), B256, 0, stream>>>(e_src, e_dst, edg, esr, erl, cnt);
  k_scan<<<dim3(1), dim3(1024), 0, stream>>>(cnt, coff);
  k_scatter<<<dim3(NEDGE/256), B256, 0, stream>>>(edg, coff, cnt2, csr);

  /* ---- inputs -> X ---- */
  for (int t=0;t<5;t++)
    hipMemcpyAsync(X + (size_t)h_OFFS[t]*384, xin[t], (size_t)h_NT[t]*384*4,
                   hipMemcpyDeviceToDevice, stream);

  /* ---- HGT layers ---- */
  for (int l=0;l<2;l++){
    /* combined 5-type KQV projection: one 64x128-tile launch, per-tile type select */
    gemm128<<<dim3(9, 128), B256, 0, stream>>>(
        X, 384, 0,
        Wkqv + (size_t)l*5*442368, 1152, 442368,
        bkqv + (size_t)l*5*1152, 1152,
        KQV, 1152, 0, 8192, 1152, 384, 0, 0, 1 /*tsel*/,
        nullptr, nullptr, nullptr, nullptr);
    gemm_rel<<<dim3(2,32,64), B256, 0, stream>>>(
        KQV, krel + (size_t)l*294912, vrel + (size_t)l*294912, KE, VE);
    k_escore<<<dim3(NEDGE/4), B256, 0, stream>>>(KQV, KE, edg, esr, erl, prel + (size_t)l*32, EA);
    hipMemsetAsync(EMX, 0, 8192*4*4, stream);
    hipMemsetAsync(EDEN, 0, 8192*4*4, stream);
    k_segmax<<<dim3(NEDGE*4/256), B256, 0, stream>>>(EA, edg, EMX);
    k_expsum<<<dim3(NEDGE*4/256), B256, 0, stream>>>(EA, edg, EMX, EDEN);
    k_agg<<<dim3(NTOT), dim3(128), 0, stream>>>(EA, VE, EDEN, csr, coff, esr, AGG);
    /* combined 5-type Wout projection (gelu on A) */
    gemm128<<<dim3(3, 128), B256, 0, stream>>>(
        AGG, 384, 0,
        Wout + (size_t)l*5*147456, 384, 147456,
        bout + (size_t)l*5*384, 384,
        OWT, 384, 0, 8192, 384, 384, 0, 1 /*agelu*/, 1 /*tsel*/,
        nullptr, nullptr, nullptr, nullptr);
    k_gateln<<<dim3(NTOT), dim3(128), 0, stream>>>(OWT, X, skp + l*5, lng, lnb);
  }

  const float* user_h   = X;
  const float* ai_h     = X + (size_t)2048*384;
  const float* stance_h = X + (size_t)4096*384;
  const float* belief_h = X + (size_t)7168*384;

  /* ---- hs, xg ---- */
  gemm_big(stance_h, 384, sp_W, 384, sp_b, TMPA, 384, 2048, 384, 384, 0, 0);
  k_lnrow<<<dim3(2048), dim3(128), 0, stream>>>(TMPA, HS, sp_lng, sp_lnb, 0 /*gelu*/);
  gemm(HS, 384, fc0_W, 384, fc0_b, bn_g, bn_b, BNCONST, XG, 384, 2048, 384, 384, 1 /*relu*/, 0);

  /* ---- linear-attention blocks ---- */
  for (int i=0;i<2;i++){
    /* q/k/v projections batched into one launch: z selects weight/bias pointer,
       C strided (QB,KB,VB contiguous in arena) */
    gemm128<<<dim3(12,32,3), B256, 0, stream>>>(
        XG, 384, 0,
        tq_W + (size_t)i*589824, 1536, 0,
        tq_b + (size_t)i*1536, 0,
        QB, 1536, 2048*1536,
        2048, 1536, 384, 0, 0, 0,
        tk_W + (size_t)i*589824, tv_W + (size_t)i*589824,
        tk_b + (size_t)i*1536, tv_b + (size_t)i*1536);
    hipMemsetAsync(SQSK, 0, 8, stream);
    k_sumsq<<<dim3(512), B256, 0, stream>>>(QB, 2048*1536, SQSK);
    k_sumsq<<<dim3(512), B256, 0, stream>>>(KB, 2048*1536, SQSK+1);
    hipMemsetAsync(KSUM, 0, 1536*4, stream);
    k_colsum<<<dim3(6,8), B256, 0, stream>>>(KB, 2048, 1536, 1.0f, KSUM);
    k_dnm<<<dim3(2048), B256, 0, stream>>>(QB, KSUM, SQSK, DNM);
    hipMemsetAsync(KVS, 0, (size_t)4*147456*4, stream);
    gemm_atb_ks<<<dim3(6,6,32), B256, 0, stream>>>(KB, 1536, VB, 1536, KVS, 384,
        384, 384, 2048, 384, 384, 147456, 8);
    /* 4-head ZNUM batched via grid.z */
    gemm128<<<dim3(3,32,4), B256, 0, stream>>>(
        QB, 1536, 384, KVS, 384, 147456,
        nullptr, 0, ZNUM, 1536, 384, 2048, 384, 384, 0, 0, 0,
        nullptr, nullptr, nullptr, nullptr);
    k_zcomb<<<dim3(3072), B256, 0, stream>>>(ZNUM, VB, DNM, SQSK, XG,
        bn_g + (size_t)(i+1)*384, bn_b + (size_t)(i+1)*384);
  }

  /* ---- h_mixed ---- */
  k_mix<<<dim3(3072), B256, 0, stream>>>(HS, XG, HM, 2048*384, 0.7f, 0.3f);

  /* ---- MHA helper (flash); projections on gemm128, fused when qin==kvin ---- */
  auto run_mha = [&](const float* qin, int nq, const float* kvin, int nkv, int mi, float* OUT){
    const float* Wq = mWqkv + (size_t)mi*442368;
    const float* bq = mbqkv + (size_t)mi*1152;
    if (qin == kvin){
      gemm_big(qin, 384, Wq, 1152, bq, MQKV, 1152, nq, 1152, 384, 0, 0);
    } else {
      gemm_big(qin, 384, Wq, 1152, bq, MQKV, 1152, nq, 384, 384, 0, 0);
      gemm_big(kvin, 384, Wq + 384, 1152, bq + 384, MQKV + 384, 1152, nkv, 768, 384, 0, 0);
    }
    int nch = nkv / 512;
    fa_kernel<<<dim3(nq/64, 4, nch), B256, 0, stream>>>(MQKV, nq, OPART, MLBUF);
    k_famerge<<<dim3((4*nq*96 + 255)/256), B256, 0, stream>>>(OPART, MLBUF, AO, nq, nch);
    gemm_big(AO, 384, mWo + (size_t)mi*147456, 384, mbo + (size_t)mi*384,
             OUT, 384, nq, 384, 384, 0, 0);
  };

  /* ---- traj ---- */
  run_mha(HM, 2048, HM, 2048, 1, TRAJ);
  hipMemsetAsync(TRAJSUM, 0, 576*4, stream);
  k_colsum<<<dim3(2,8), B256, 0, stream>>>(TRAJ, 2048, 384, 1.0f/2048.0f, TRAJSUM);

  /* ---- conv path (im2col + GEMM, gelu epilogue) ---- */
  k_im2col<<<dim3(2048*1152/256), B256, 0, stream>>>(HM, IMC);
  k_wtr<<<dim3((384*1152+255)/256), B256, 0, stream>>>(c1W, WT, 384);
  gemm_big(IMC, 1152, WT, 384, c1b, C1O, 384, 2048, 384, 1152, 2 /*gelu*/, 0);
  k_im2col<<<dim3(2048*1152/256), B256, 0, stream>>>(C1O, IMC);
  k_wtr<<<dim3((192*1152+255)/256), B256, 0, stream>>>(c2W, WT, 192);
  gemm_big(IMC, 1152, WT, 192, c2b, C2O, 192, 2048, 192, 1152, 2 /*gelu*/, 0);
  k_colsum<<<dim3(1,8), B256, 0, stream>>>(C2O, 2048, 192, 1.0f/2048.0f, DECAYSUM);

  /* ---- traj_emb ---- */
  gemv(TRAJSUM, 576, opW, 384, opb, TEMB, 384, 0);

  /* ---- ai_ctx ---- */
  run_mha(ai_h, 2048, user_h, 2048, 0, AICTX);
  hipMemsetAsync(AIPOOL, 0, 384*4, stream);
  k_colsum<<<dim3(2,8), B256, 0, stream>>>(AICTX, 2048, 384, 1.0f/2048.0f, AIPOOL);

  /* ---- pscores ---- */
  k_comb<<<dim3(6144), B256, 0, stream>>>(ai_h, user_h, CB);
  gemm_big(CB, 768, as1W, 384, as1b, PT, 384, 2048, 384, 768, 1, 0);
  k_rowdot<<<dim3(512), B256, 0, stream>>>(PT, 384, 384, as2W, as2b, out + 2 + 2048, 2048);

  /* ---- bctx ---- */
  run_mha(ai_h, 2048, belief_h, 1024, 2, TRAJ);
  hipMemsetAsync(BCTXV, 0, 384*4, stream);
  k_colsum<<<dim3(2,8), B256, 0, stream>>>(TRAJ, 2048, 384, 1.0f/2048.0f, BCTXV);

  /* ---- stance delta ---- */
  hipMemcpyAsync(SDIN, stance_h, 384*4, hipMemcpyDeviceToDevice, stream);
  hipMemcpyAsync(SDIN + 384, stance_h + (size_t)2047*384, 384*4, hipMemcpyDeviceToDevice, stream);
  gemv(SDIN, 768, sc1W, 384, sc1b, T1, 384, 1);
  gemv(T1, 384, sc2W, 192, sc2b, SDELT, 192, 0);

  /* ---- classifier ---- */
  gemv(TEMB, 1344, cl1W, 384, cl1b, Z1, 384, 0);
  k_lnrow<<<dim3(1), dim3(128), 0, stream>>>(Z1, Zb, cllng, cllnb, 1 /*relu*/);
  gemv(Zb, 384, cl2W, 192, cl2b, Z2, 192, 1);
  k_final<<<dim3(1), dim3(64), 0, stream>>>(Z2, cl3W, cl3b, out);

  /* ---- per_turn ---- */
  k_rowdot<<<dim3(512), B256, 0, stream>>>(AICTX, 384, 384, tpW, tpb, out + 2, 2048);
}

// Round 8
// 2867.625 us; speedup vs baseline: 1.0486x; 1.0486x over previous
//
#include <hip/hip_runtime.h>
#include <hip/hip_bf16.h>

#define NEDGE 229376
#define NTOT  8192
#define BNCONST 0.9999950000374997f   /* 1/sqrt(1+1e-5) */
#define ISQ96   0.10206207261596575f  /* 1/sqrt(96) */

__constant__ int c_NT[5]     = {2048,2048,2048,1024,1024};
__constant__ int c_OFFS[5]   = {0,2048,4096,6144,7168};
__constant__ int c_ESRC[8]   = {0,1,1,2,0,3,1,4};
__constant__ int c_EDST[8]   = {1,0,2,2,3,1,4,2};
__constant__ int c_EOFF[9]   = {0,32768,65536,98304,131072,147456,180224,196608,229376};
__constant__ int c_RELROW[8] = {0,2048,4096,6144,8192,10240,11264,13312};

static const int h_NT[5]   = {2048,2048,2048,1024,1024};
static const int h_OFFS[5] = {0,2048,4096,6144,7168};

__device__ inline float gelu_f(float x){ return 0.5f*x*(1.0f+erff(x*0.70710678118654752f)); }
__device__ inline float sigm(float x){ return 1.0f/(1.0f+expf(-x)); }
__device__ inline float wsum64(float v){
  #pragma unroll
  for (int s=32;s>0;s>>=1) v += __shfl_xor(v, s, 64);
  return v;
}
__device__ inline unsigned encf(float f){
  unsigned b = __float_as_uint(f);
  return (b & 0x80000000u) ? ~b : (b | 0x80000000u);
}
__device__ inline float decf(unsigned u){
  unsigned b = (u & 0x80000000u) ? (u & 0x7FFFFFFFu) : ~u;
  return __uint_as_float(b);
}
__device__ inline int row_type(int row){
  return (row<2048)?0:((row<4096)?1:((row<6144)?2:((row<7168)?3:4)));
}
/* reduce across the 16-lane row group (lanes ty*16..+15) */
__device__ inline float rgmax(float v){
  v = fmaxf(v, __shfl_xor(v, 1, 64));
  v = fmaxf(v, __shfl_xor(v, 2, 64));
  v = fmaxf(v, __shfl_xor(v, 4, 64));
  v = fmaxf(v, __shfl_xor(v, 8, 64));
  return v;
}
__device__ inline float rgsum(float v){
  v += __shfl_xor(v, 1, 64);
  v += __shfl_xor(v, 2, 64);
  v += __shfl_xor(v, 4, 64);
  v += __shfl_xor(v, 8, 64);
  return v;
}

/* ---------------- simple utility kernels ---------------- */

__global__ void k_mix(const float* __restrict__ a, const float* __restrict__ b,
                      float* __restrict__ c, int n, float fa, float fb){
  int i = blockIdx.x*256 + threadIdx.x;
  if (i < n) c[i] = fa*a[i] + fb*b[i];
}

__global__ void k_comb(const float* __restrict__ ai, const float* __restrict__ user,
                       float* __restrict__ cb){
  int i = blockIdx.x*256 + threadIdx.x;
  if (i >= 2048*768) return;
  int n = i / 768, c = i - n*768;
  cb[i] = (c < 384) ? ai[n*384 + c] : user[n*384 + (c-384)];
}

/* ---------------- edge preprocessing (CSR by destination) ---------------- */

__global__ void k_edge_pre(const int* __restrict__ esrc, const int* __restrict__ edst,
                           int* edg, int* esr, int* erl, int* cnt){
  int e = blockIdx.x*256 + threadIdx.x;
  if (e >= NEDGE) return;
  int r = 0;
  #pragma unroll
  for (int q=1;q<8;q++) if (e >= c_EOFF[q]) r = q;
  int dg = c_OFFS[c_EDST[r]] + edst[e];
  edg[e] = dg;
  esr[e] = c_RELROW[r] + esrc[e];
  erl[e] = r;
  atomicAdd(&cnt[dg], 1);
}

__global__ __launch_bounds__(1024) void k_scan(const int* __restrict__ cnt, int* __restrict__ off){
  __shared__ int sh[1024];
  int tid = threadIdx.x;
  int base = tid*8;
  int loc[8]; int run = 0;
  #pragma unroll
  for (int i=0;i<8;i++){ loc[i] = run; run += cnt[base+i]; }
  sh[tid] = run;
  __syncthreads();
  for (int d=1; d<1024; d<<=1){
    int v = (tid >= d) ? sh[tid-d] : 0;
    __syncthreads();
    sh[tid] += v;
    __syncthreads();
  }
  int pre = (tid==0) ? 0 : sh[tid-1];
  #pragma unroll
  for (int i=0;i<8;i++) off[base+i] = pre + loc[i];
  if (tid==1023) off[8192] = sh[1023];
}

__global__ void k_scatter(const int* __restrict__ edg, const int* __restrict__ off,
                          int* cnt2, int* csr){
  int e = blockIdx.x*256 + threadIdx.x;
  if (e >= NEDGE) return;
  int dg = edg[e];
  int pos = off[dg] + atomicAdd(&cnt2[dg], 1);
  csr[pos] = e;
}

/* ------- tiled GEMMs: 64x64 tile, 4x4 microtile, double-buffered + float4 stage ------- */

__global__ __launch_bounds__(256) void gemm_f(
    const float* __restrict__ A, int lda, const float* __restrict__ B, int ldb,
    const float* __restrict__ bias, const float* __restrict__ cs, const float* __restrict__ csh,
    float kmul, float* __restrict__ C, int ldc, int M, int N, int K, int act, int agelu)
{
  __shared__ float As[2][16][68];
  __shared__ float Bs[2][16][68];
  int tid = threadIdx.x;
  int tx = tid & 15, ty = tid >> 4;
  int am = tid >> 2, ak = (tid & 3) * 4;
  int bk = tid >> 4, bn = (tid & 15) * 4;
  int m0 = blockIdx.y * 64, n0 = blockIdx.x * 64;
  int gmA = m0 + am;
  int gnB = n0 + bn;
  int ntiles = K >> 4;
  float4 ra, rb;
  float acc[4][4] = {};

  auto fetch = [&](int kk){
    if (gmA < M){
      ra = *reinterpret_cast<const float4*>(&A[(size_t)gmA*lda + kk + ak]);
      if (agelu){ ra.x=gelu_f(ra.x); ra.y=gelu_f(ra.y); ra.z=gelu_f(ra.z); ra.w=gelu_f(ra.w); }
    } else ra = make_float4(0.f,0.f,0.f,0.f);
    if (gnB + 3 < N){
      rb = *reinterpret_cast<const float4*>(&B[(size_t)(kk + bk)*ldb + gnB]);
    } else {
      rb.x = (gnB   < N) ? B[(size_t)(kk + bk)*ldb + gnB  ] : 0.f;
      rb.y = (gnB+1 < N) ? B[(size_t)(kk + bk)*ldb + gnB+1] : 0.f;
      rb.z = (gnB+2 < N) ? B[(size_t)(kk + bk)*ldb + gnB+2] : 0.f;
      rb.w = (gnB+3 < N) ? B[(size_t)(kk + bk)*ldb + gnB+3] : 0.f;
    }
  };
  auto stage = [&](int b){
    As[b][ak  ][am] = ra.x;
    As[b][ak+1][am] = ra.y;
    As[b][ak+2][am] = ra.z;
    As[b][ak+3][am] = ra.w;
    *reinterpret_cast<float4*>(&Bs[b][bk][bn]) = rb;
  };

  fetch(0);
  stage(0);
  __syncthreads();
  for (int t = 0; t < ntiles; t++){
    int cur = t & 1;
    if (t + 1 < ntiles) fetch((t+1) << 4);
    #pragma unroll
    for (int k = 0; k < 16; k++) {
      float4 a4 = *reinterpret_cast<const float4*>(&As[cur][k][ty*4]);
      float4 b4 = *reinterpret_cast<const float4*>(&Bs[cur][k][tx*4]);
      float a[4] = {a4.x, a4.y, a4.z, a4.w};
      float b[4] = {b4.x, b4.y, b4.z, b4.w};
      #pragma unroll
      for (int i=0;i<4;i++)
        #pragma unroll
        for (int j=0;j<4;j++) acc[i][j] += a[i]*b[j];
    }
    if (t + 1 < ntiles) stage(cur ^ 1);
    __syncthreads();
  }
  #pragma unroll
  for (int i=0;i<4;i++){
    int gm = m0 + ty*4 + i; if (gm >= M) continue;
    #pragma unroll
    for (int j=0;j<4;j++){
      int gn = n0 + tx*4 + j; if (gn >= N) continue;
      float v = acc[i][j];
      if (bias) v += bias[gn];
      float s = kmul;
      if (cs) s *= cs[gn];
      v *= s;
      if (csh) v += csh[gn];
      if (act==1) v = fmaxf(v, 0.f);
      else if (act==2) v = gelu_f(v);
      C[(size_t)gm*ldc + gn] = v;
    }
  }
}

/* ------- big GEMM v3: 64x128 tile, 4x8 SPLIT microtile, SINGLE-buffered LDS.
   Natural VGPR ~100-120 (plain launch_bounds(256) — min-waves arg spills on
   this toolchain, R3/R4), 12.8KB LDS -> 4 blocks/CU, prefetch-into-regs
   hides global latency. Verified R5: 3388->2911 on KQV/Wout/qkv/ZNUM sites.
   R8 note: only use at >=~200 blocks (R6: 96-block launches regressed). */
__global__ __launch_bounds__(256) void gemm128(
    const float* __restrict__ A, int lda, int sAz,
    const float* __restrict__ B, int ldb, int sBz,
    const float* __restrict__ bias, int sbz,
    float* __restrict__ C, int ldc, int sCz,
    int M, int N, int K, int act, int agelu, int tsel,
    const float* __restrict__ Bp1, const float* __restrict__ Bp2,
    const float* __restrict__ biasp1, const float* __restrict__ biasp2)
{
  __shared__ float As[16][68];
  __shared__ float Bs[16][132];
  int tid = threadIdx.x;
  int tx = tid & 15, ty = tid >> 4;
  int am = tid >> 2, ak = (tid & 3) * 4;
  int bk = tid >> 4, bn = (tid & 15) * 4;

  /* XCD-chunked bijective swizzle of the xy-plane block id (m204 formula) */
  int nxy = gridDim.x * gridDim.y;
  int orig = blockIdx.y * gridDim.x + blockIdx.x;
  int q = nxy >> 3, r = nxy & 7;
  int xcd = orig & 7, rest = orig >> 3;
  int wg = ((xcd < r) ? xcd*(q+1) : r*(q+1) + (xcd - r)*q) + rest;
  int bx = wg % gridDim.x, by = wg / gridDim.x;
  int m0 = by * 64, n0 = bx * 128;

  int z = blockIdx.z;
  const float* Ab = A + (size_t)z * sAz;
  const float* Bb;
  const float* bb;
  if (Bp1){
    Bb = (z == 0) ? B : ((z == 1) ? Bp1 : Bp2);
    bb = (z == 0) ? bias : ((z == 1) ? biasp1 : biasp2);
  } else {
    Bb = B + (size_t)z * sBz;
    bb = bias ? (bias + (size_t)z * sbz) : nullptr;
  }
  float* Cb = C + (size_t)z * sCz;
  if (tsel){
    int t = row_type(m0);
    Bb = B + (size_t)t * sBz;
    bb = bias ? (bias + (size_t)t * sbz) : nullptr;
  }
  int gmA = m0 + am, gnB = n0 + bn;
  int ntiles = K >> 4;
  float4 ra, rb0, rb1;
  float acc[4][8] = {};

  auto fetch = [&](int kk){
    if (gmA < M){
      ra = *reinterpret_cast<const float4*>(&Ab[(size_t)gmA*lda + kk + ak]);
      if (agelu){
        ra.x=gelu_f(ra.x); ra.y=gelu_f(ra.y); ra.z=gelu_f(ra.z); ra.w=gelu_f(ra.w);
      }
    } else {
      ra = make_float4(0.f,0.f,0.f,0.f);
    }
    if (gnB + 67 < N){
      rb0 = *reinterpret_cast<const float4*>(&Bb[(size_t)(kk + bk)*ldb + gnB]);
      rb1 = *reinterpret_cast<const float4*>(&Bb[(size_t)(kk + bk)*ldb + gnB + 64]);
    } else {
      const float* bp = &Bb[(size_t)(kk + bk)*ldb];
      rb0.x = (gnB    < N) ? bp[gnB   ] : 0.f;
      rb0.y = (gnB+1  < N) ? bp[gnB+ 1] : 0.f;
      rb0.z = (gnB+2  < N) ? bp[gnB+ 2] : 0.f;
      rb0.w = (gnB+3  < N) ? bp[gnB+ 3] : 0.f;
      rb1.x = (gnB+64 < N) ? bp[gnB+64] : 0.f;
      rb1.y = (gnB+65 < N) ? bp[gnB+65] : 0.f;
      rb1.z = (gnB+66 < N) ? bp[gnB+66] : 0.f;
      rb1.w = (gnB+67 < N) ? bp[gnB+67] : 0.f;
    }
  };
  auto stage = [&](){
    As[ak  ][am] = ra.x;
    As[ak+1][am] = ra.y;
    As[ak+2][am] = ra.z;
    As[ak+3][am] = ra.w;
    *reinterpret_cast<float4*>(&Bs[bk][bn     ]) = rb0;
    *reinterpret_cast<float4*>(&Bs[bk][bn + 64]) = rb1;
  };

  fetch(0);
  for (int t = 0; t < ntiles; t++){
    if (t > 0) __syncthreads();
    stage();
    __syncthreads();
    if (t + 1 < ntiles) fetch((t+1) << 4);
    #pragma unroll
    for (int k = 0; k < 16; k++) {
      float4 a4 = *reinterpret_cast<const float4*>(&As[k][ty*4]);
      float4 b0 = *reinterpret_cast<const float4*>(&Bs[k][tx*4]);
      float4 b1 = *reinterpret_cast<const float4*>(&Bs[k][64 + tx*4]);
      float a[4] = {a4.x,a4.y,a4.z,a4.w};
      float b[8] = {b0.x,b0.y,b0.z,b0.w,b1.x,b1.y,b1.z,b1.w};
      #pragma unroll
      for (int i=0;i<4;i++)
        #pragma unroll
        for (int j=0;j<8;j++) acc[i][j] += a[i]*b[j];
    }
  }

  bool fullN = (n0 + 127 < N);
  int cb0 = n0 + tx*4, cb1 = n0 + 64 + tx*4;
  #pragma unroll
  for (int i=0;i<4;i++){
    int gm = m0 + ty*4 + i;
    if (gm >= M) continue;
    float v[8];
    #pragma unroll
    for (int jh=0; jh<2; jh++){
      #pragma unroll
      for (int j=0;j<4;j++){
        float x = acc[i][jh*4+j];
        int gn = (jh ? cb1 : cb0) + j;
        if (bb && gn < N) x += bb[gn];
        if (act==1) x = fmaxf(x, 0.f);
        else if (act==2) x = gelu_f(x);
        v[jh*4+j] = x;
      }
    }
    if (fullN){
      *reinterpret_cast<float4*>(&Cb[(size_t)gm*ldc + cb0]) = make_float4(v[0],v[1],v[2],v[3]);
      *reinterpret_cast<float4*>(&Cb[(size_t)gm*ldc + cb1]) = make_float4(v[4],v[5],v[6],v[7]);
    } else {
      #pragma unroll
      for (int jh=0; jh<2; jh++){
        #pragma unroll
        for (int j=0;j<4;j++){
          int gn = (jh ? cb1 : cb0) + j;
          if (gn < N) Cb[(size_t)gm*ldc + gn] = v[jh*4+j];
        }
      }
    }
  }
}

/* batched HGT relation projection as GEMM: z = (r*4+h)*2 + w */
__global__ __launch_bounds__(256) void gemm_rel(
    const float* __restrict__ KQV_, const float* __restrict__ krel_l,
    const float* __restrict__ vrel_l, float* __restrict__ KE_, float* __restrict__ VE_)
{
  int z = blockIdx.z;
  int w = z & 1, h = (z >> 1) & 3, r = z >> 3;
  int s = c_ESRC[r];
  int Ns = c_NT[s];
  int m0 = blockIdx.y * 64;
  if (m0 >= Ns) return;
  int n0 = blockIdx.x * 64;
  const float* A = KQV_ + (size_t)c_OFFS[s]*1152 + (w ? 768 : 0) + h*96;
  const float* B = (w ? vrel_l : krel_l) + (size_t)(r*4 + h)*9216;
  float* C = (w ? VE_ : KE_) + (size_t)c_RELROW[r]*384 + h*96;

  __shared__ float As[2][16][68];
  __shared__ float Bs[2][16][68];
  int tid = threadIdx.x;
  int tx = tid & 15, ty = tid >> 4;
  int am = tid >> 2, ak = (tid & 3) * 4;
  int bk = tid >> 4, bn = (tid & 15) * 4;
  int gmA = m0 + am;
  int gnB = n0 + bn;
  float4 ra, rb;
  float acc[4][4] = {};

  auto fetch = [&](int kk){
    ra = (gmA < Ns) ? *reinterpret_cast<const float4*>(&A[(size_t)gmA*1152 + kk + ak])
                    : make_float4(0.f,0.f,0.f,0.f);
    if (gnB + 3 < 96){
      rb = *reinterpret_cast<const float4*>(&B[(size_t)(kk + bk)*96 + gnB]);
    } else {
      rb.x = (gnB   < 96) ? B[(size_t)(kk + bk)*96 + gnB  ] : 0.f;
      rb.y = (gnB+1 < 96) ? B[(size_t)(kk + bk)*96 + gnB+1] : 0.f;
      rb.z = (gnB+2 < 96) ? B[(size_t)(kk + bk)*96 + gnB+2] : 0.f;
      rb.w = (gnB+3 < 96) ? B[(size_t)(kk + bk)*96 + gnB+3] : 0.f;
    }
  };
  auto stage = [&](int b){
    As[b][ak  ][am] = ra.x;
    As[b][ak+1][am] = ra.y;
    As[b][ak+2][am] = ra.z;
    As[b][ak+3][am] = ra.w;
    *reinterpret_cast<float4*>(&Bs[b][bk][bn]) = rb;
  };

  fetch(0);
  stage(0);
  __syncthreads();
  for (int t = 0; t < 6; t++){
    int cur = t & 1;
    if (t + 1 < 6) fetch((t+1) << 4);
    #pragma unroll
    for (int k = 0; k < 16; k++) {
      float4 a4 = *reinterpret_cast<const float4*>(&As[cur][k][ty*4]);
      float4 b4 = *reinterpret_cast<const float4*>(&Bs[cur][k][tx*4]);
      float a[4] = {a4.x, a4.y, a4.z, a4.w};
      float b[4] = {b4.x, b4.y, b4.z, b4.w};
      #pragma unroll
      for (int i=0;i<4;i++)
        #pragma unroll
        for (int j=0;j<4;j++) acc[i][j] += a[i]*b[j];
    }
    if (t + 1 < 6) stage(cur ^ 1);
    __syncthreads();
  }
  #pragma unroll
  for (int i=0;i<4;i++){
    int gm = m0 + ty*4 + i; if (gm >= Ns) continue;
    #pragma unroll
    for (int j=0;j<4;j++){
      int gn = n0 + tx*4 + j; if (gn >= 96) continue;
      C[(size_t)gm*384 + gn] = acc[i][j];
    }
  }
}

// C[m,n] += sum_l A[l,m]*B[l,n], head-batched + L-split (atomic accumulate).
__global__ __launch_bounds__(256) void gemm_atb_ks(
    const float* __restrict__ A0, int lda, const float* __restrict__ B0, int ldb,
    float* __restrict__ C0, int ldc, int M, int N, int L,
    int hsA, int hsB, int hsC, int nch)
{
  __shared__ float As[2][16][68];
  __shared__ float Bs[2][16][68];
  int h = blockIdx.z / nch, c = blockIdx.z % nch;
  const float* A = A0 + (size_t)h*hsA;
  const float* B = B0 + (size_t)h*hsB;
  float* C = C0 + (size_t)h*hsC;
  int l0 = c*256;
  int tid = threadIdx.x;
  int tx = tid & 15, ty = tid >> 4;
  int sl = tid >> 4, sq = (tid & 15) * 4;
  int m0 = blockIdx.y * 64, n0 = blockIdx.x * 64;
  int gmA = m0 + sq, gnB = n0 + sq;
  int ntiles = 16;
  float4 ra, rb;
  float acc[4][4] = {};

  auto fetch = [&](int ll){
    if (gmA + 3 < M){
      ra = *reinterpret_cast<const float4*>(&A[(size_t)(ll + sl)*lda + gmA]);
    } else {
      ra.x = (gmA   < M) ? A[(size_t)(ll + sl)*lda + gmA  ] : 0.f;
      ra.y = (gmA+1 < M) ? A[(size_t)(ll + sl)*lda + gmA+1] : 0.f;
      ra.z = (gmA+2 < M) ? A[(size_t)(ll + sl)*lda + gmA+2] : 0.f;
      ra.w = (gmA+3 < M) ? A[(size_t)(ll + sl)*lda + gmA+3] : 0.f;
    }
    if (gnB + 3 < N){
      rb = *reinterpret_cast<const float4*>(&B[(size_t)(ll + sl)*ldb + gnB]);
    } else {
      rb.x = (gnB   < N) ? B[(size_t)(ll + sl)*ldb + gnB  ] : 0.f;
      rb.y = (gnB+1 < N) ? B[(size_t)(ll + sl)*ldb + gnB+1] : 0.f;
      rb.z = (gnB+2 < N) ? B[(size_t)(ll + sl)*ldb + gnB+2] : 0.f;
      rb.w = (gnB+3 < N) ? B[(size_t)(ll + sl)*ldb + gnB+3] : 0.f;
    }
  };
  auto stage = [&](int b){
    *reinterpret_cast<float4*>(&As[b][sl][sq]) = ra;
    *reinterpret_cast<float4*>(&Bs[b][sl][sq]) = rb;
  };

  fetch(l0);
  stage(0);
  __syncthreads();
  for (int t = 0; t < ntiles; t++){
    int cur = t & 1;
    if (t + 1 < ntiles) fetch(l0 + ((t+1) << 4));
    #pragma unroll
    for (int l = 0; l < 16; l++) {
      float4 a4 = *reinterpret_cast<const float4*>(&As[cur][l][ty*4]);
      float4 b4 = *reinterpret_cast<const float4*>(&Bs[cur][l][tx*4]);
      float a[4] = {a4.x, a4.y, a4.z, a4.w};
      float b[4] = {b4.x, b4.y, b4.z, b4.w};
      #pragma unroll
      for (int i=0;i<4;i++)
        #pragma unroll
        for (int j=0;j<4;j++) acc[i][j] += a[i]*b[j];
    }
    if (t + 1 < ntiles) stage(cur ^ 1);
    __syncthreads();
  }
  #pragma unroll
  for (int i=0;i<4;i++){
    int gm = m0 + ty*4 + i; if (gm >= M) continue;
    #pragma unroll
    for (int j=0;j<4;j++){
      int gn = n0 + tx*4 + j; if (gn >= N) continue;
      atomicAdd(&C[(size_t)gm*ldc + gn], acc[i][j]);
    }
  }
}

/* ---------------- flash attention v1 + K/V register prefetch ----------------
   R8: v1 structure restored (R7's 64-kv restructure serialized: 192us, VALU 31%).
   Added: next tile's K/V global loads issued into registers right after the
   stage barrier, overlapping HBM/L2 latency with S+PV compute. LDS unchanged
   (62464B, 2 blocks/CU); VGPR +24 is free (LDS-bound occupancy).
   grid (nq/64, 4 heads, nkv/512); MQKV row*1152: Q[0..383] K[384..767] V[768..1151] */
__global__ __launch_bounds__(256) void fa_kernel(
    const float* __restrict__ MQ, int nq, float* __restrict__ OP, float* __restrict__ ML)
{
  __shared__ float Qs[96][68];
  __shared__ float Ksf[96][36];
  __shared__ float Vs[32][104];
  __shared__ float Ps[64][36];
  int tid = threadIdx.x;
  int tx = tid & 15, ty = tid >> 4;
  int q0 = blockIdx.x * 64;
  int h = blockIdx.y;
  int z = blockIdx.z, nch = gridDim.z;
  int kvbase = z * 512;

  /* stage Q tile [k][r] */
  #pragma unroll
  for (int i = 0; i < 6; i++){
    int e = tid + i*256;
    int r = e & 63, kq = (e >> 6) * 4;
    float4 f = *reinterpret_cast<const float4*>(&MQ[(size_t)(q0+r)*1152 + h*96 + kq]);
    Qs[kq  ][r] = f.x;
    Qs[kq+1][r] = f.y;
    Qs[kq+2][r] = f.z;
    Qs[kq+3][r] = f.w;
  }

  float m_i[4], l_i[4], acc[4][6];
  #pragma unroll
  for (int i=0;i<4;i++){
    m_i[i] = -3.0e38f; l_i[i] = 0.f;
    #pragma unroll
    for (int c=0;c<6;c++) acc[i][c] = 0.f;
  }
  int c0 = tx*6;

  /* per-thread staging coordinates (constant) */
  int kn[3], kk4[3], vn[3], vc4[3];
  #pragma unroll
  for (int i=0;i<3;i++){
    int e = tid + i*256;
    kn[i] = e & 31;  kk4[i] = (e >> 5) * 4;
    vn[i] = e / 24;  vc4[i] = (e - vn[i]*24) * 4;
  }
  float4 kf[3], vf[3];
  auto fetchKV = [&](int t){
    int kv0 = kvbase + t*32;
    #pragma unroll
    for (int i=0;i<3;i++){
      kf[i] = *reinterpret_cast<const float4*>(&MQ[(size_t)(kv0+kn[i])*1152 + 384 + h*96 + kk4[i]]);
      vf[i] = *reinterpret_cast<const float4*>(&MQ[(size_t)(kv0+vn[i])*1152 + 768 + h*96 + vc4[i]]);
    }
  };
  auto stageKV = [&](){
    #pragma unroll
    for (int i=0;i<3;i++){
      Ksf[kk4[i]  ][kn[i]] = kf[i].x;
      Ksf[kk4[i]+1][kn[i]] = kf[i].y;
      Ksf[kk4[i]+2][kn[i]] = kf[i].z;
      Ksf[kk4[i]+3][kn[i]] = kf[i].w;
      *reinterpret_cast<float4*>(&Vs[vn[i]][vc4[i]]) = vf[i];
    }
  };

  fetchKV(0);

  for (int t = 0; t < 16; t++){
    if (t == 0) __syncthreads();  /* Q staged (and nothing reads K/V yet) */
    stageKV();
    __syncthreads();              /* K/V visible */
    if (t + 1 < 16) fetchKV(t+1); /* loads in flight under S+PV compute */

    /* S = Q @ K^T (64x32), thread: rows ty*4..+3, kv cols tx*2..+1 */
    float s0[4] = {0,0,0,0}, s1[4] = {0,0,0,0};
    #pragma unroll 8
    for (int k = 0; k < 96; k++){
      float4 a4 = *reinterpret_cast<const float4*>(&Qs[k][ty*4]);
      float2 b2 = *reinterpret_cast<const float2*>(&Ksf[k][tx*2]);
      s0[0] += a4.x*b2.x; s1[0] += a4.x*b2.y;
      s0[1] += a4.y*b2.x; s1[1] += a4.y*b2.y;
      s0[2] += a4.z*b2.x; s1[2] += a4.z*b2.y;
      s0[3] += a4.w*b2.x; s1[3] += a4.w*b2.y;
    }
    /* online softmax per row */
    #pragma unroll
    for (int i=0;i<4;i++){
      float a = s0[i]*ISQ96, b = s1[i]*ISQ96;
      float rm = rgmax(fmaxf(a, b));
      float mn = fmaxf(m_i[i], rm);
      float alpha = expf(m_i[i] - mn);
      float p0 = expf(a - mn), p1 = expf(b - mn);
      float rs = rgsum(p0 + p1);
      l_i[i] = l_i[i]*alpha + rs;
      m_i[i] = mn;
      #pragma unroll
      for (int c=0;c<6;c++) acc[i][c] *= alpha;
      Ps[ty*4+i][tx*2  ] = p0;
      Ps[ty*4+i][tx*2+1] = p1;
    }
    __syncthreads();
    /* O += P @ V : thread rows ty*4..+3, cols c0..c0+5 */
    for (int kv = 0; kv < 32; kv++){
      float2 v01 = *reinterpret_cast<const float2*>(&Vs[kv][c0]);
      float2 v23 = *reinterpret_cast<const float2*>(&Vs[kv][c0+2]);
      float2 v45 = *reinterpret_cast<const float2*>(&Vs[kv][c0+4]);
      #pragma unroll
      for (int i=0;i<4;i++){
        float p = Ps[ty*4+i][kv];
        acc[i][0] += p*v01.x; acc[i][1] += p*v01.y;
        acc[i][2] += p*v23.x; acc[i][3] += p*v23.y;
        acc[i][4] += p*v45.x; acc[i][5] += p*v45.y;
      }
    }
    __syncthreads();   /* V/P reads done before next stage overwrites */
  }

  /* write unnormalized partials */
  size_t base = ((size_t)(h*nch + z)*nq + q0);
  #pragma unroll
  for (int i=0;i<4;i++){
    size_t row = base + ty*4 + i;
    #pragma unroll
    for (int c=0;c<6;c++) OP[row*96 + c0 + c] = acc[i][c];
    if (tx == 0){
      ML[row*2  ] = m_i[i];
      ML[row*2+1] = l_i[i];
    }
  }
}

__global__ void k_famerge(const float* __restrict__ OP, const float* __restrict__ ML,
                          float* __restrict__ AO_, int nq, int nch){
  int e = blockIdx.x*256 + threadIdx.x;
  int total = 4*nq*96;
  if (e >= total) return;
  int c = e % 96;
  int q = (e / 96) % nq;
  int h = e / (96*nq);
  float M = -3.0e38f;
  for (int z = 0; z < nch; z++)
    M = fmaxf(M, ML[((size_t)(h*nch+z)*nq + q)*2]);
  float L = 0.f, O = 0.f;
  for (int z = 0; z < nch; z++){
    size_t row = (size_t)(h*nch+z)*nq + q;
    float w = expf(ML[row*2] - M);
    L += ML[row*2+1]*w;
    O += OP[row*96 + c]*w;
  }
  AO_[(size_t)q*384 + h*96 + c] = O / L;
}

/* ---------------- conv1d as im2col + GEMM ---------------- */
/* imcol[p][ic*3+j] = in[p-1+j][ic] (0-pad); matches per-ic j-inner accumulation order */
__global__ void k_im2col(const float* __restrict__ in, float* __restrict__ imc){
  int e = blockIdx.x*256 + threadIdx.x;
  if (e >= 2048*1152) return;
  int p = e / 1152, k = e - p*1152;
  int ic = k / 3, j = k - ic*3;
  int gp = p - 1 + j;
  imc[e] = (gp >= 0 && gp < 2048) ? in[(size_t)gp*384 + ic] : 0.f;
}
/* WT[k][oc] = W[oc][k], K = 1152 */
__global__ void k_wtr(const float* __restrict__ W, float* __restrict__ WT, int OC){
  int e = blockIdx.x*256 + threadIdx.x;
  if (e >= OC*1152) return;
  int oc = e / 1152, k = e - oc*1152;
  WT[(size_t)k*OC + oc] = W[e];
}

/* ---------------- edge attention ---------------- */

__global__ __launch_bounds__(256) void k_escore(
    const float* __restrict__ KQV_, const float* __restrict__ KE_,
    const int* __restrict__ edg, const int* __restrict__ esr, const int* __restrict__ erl,
    const float* __restrict__ prel_l, float* __restrict__ EA)
{
  int e = blockIdx.x*4 + (threadIdx.x>>6);
  if (e >= NEDGE) return;
  int lane = threadIdx.x & 63;
  int h = lane >> 4, j = lane & 15;
  int dg = edg[e], sr = esr[e], r = erl[e];
  const float* q  = KQV_ + (size_t)dg*1152 + 384 + h*96;
  const float* ke = KE_  + (size_t)sr*384 + h*96;
  float p = 0.f;
  #pragma unroll
  for (int t=0;t<6;t++){ int d = j + t*16; p += q[d]*ke[d]; }
  p += __shfl_xor(p, 1, 64);
  p += __shfl_xor(p, 2, 64);
  p += __shfl_xor(p, 4, 64);
  p += __shfl_xor(p, 8, 64);
  if (j == 0) EA[(size_t)e*4 + h] = p * prel_l[r*4+h] * ISQ96;
}

__global__ void k_segmax(const float* __restrict__ EA, const int* __restrict__ edg,
                         unsigned* __restrict__ EMX){
  int i = blockIdx.x*256 + threadIdx.x;
  if (i >= NEDGE*4) return;
  int e = i >> 2, h = i & 3;
  atomicMax(&EMX[edg[e]*4 + h], encf(EA[i]));
}

__global__ void k_expsum(float* __restrict__ EA, const int* __restrict__ edg,
                         const unsigned* __restrict__ EMX, float* __restrict__ EDEN){
  int i = blockIdx.x*256 + threadIdx.x;
  if (i >= NEDGE*4) return;
  int e = i >> 2, h = i & 3;
  int dg = edg[e];
  float m = decf(EMX[dg*4 + h]);
  float ex = expf(EA[i] - m);
  EA[i] = ex;
  atomicAdd(&EDEN[dg*4 + h], ex);
}

__global__ __launch_bounds__(128) void k_agg(
    const float* __restrict__ EA, const float* __restrict__ VE_,
    const float* __restrict__ EDEN, const int* __restrict__ csr,
    const int* __restrict__ off, const int* __restrict__ esr, float* __restrict__ AGG)
{
  int node = blockIdx.x, tid = threadIdx.x;
  int b = off[node], e1 = off[node+1];
  int d0 = tid, d1 = tid+128, d2 = tid+256;
  int h0 = d0/96, h1 = d1/96, h2 = d2/96;
  float a0=0.f, a1=0.f, a2=0.f;
  if (e1 > b){
    float i0 = 1.0f/EDEN[node*4+h0];
    float i1 = 1.0f/EDEN[node*4+h1];
    float i2 = 1.0f/EDEN[node*4+h2];
    for (int p=b; p<e1; p++){
      int e = csr[p];
      const float* ve = VE_ + (size_t)esr[e]*384;
      const float* ea = EA + (size_t)e*4;
      a0 += ea[h0]*i0*ve[d0];
      a1 += ea[h1]*i1*ve[d1];
      a2 += ea[h2]*i2*ve[d2];
    }
  }
  AGG[(size_t)node*384 + d0] = a0;
  AGG[(size_t)node*384 + d1] = a1;
  AGG[(size_t)node*384 + d2] = a2;
}

/* ---------------- row-wise norm kernels ---------------- */

__global__ __launch_bounds__(128) void k_gateln(
    const float* __restrict__ O, float* __restrict__ X,
    const float* __restrict__ skip_l, const float* __restrict__ lng, const float* __restrict__ lnb)
{
  __shared__ float red[2];
  int row = blockIdx.x, tid = threadIdx.x;
  int t = row_type(row);
  float gt = sigm(skip_l[t]);
  const float* o = O + (size_t)row*384;
  float* x = X + (size_t)row*384;
  float v0 = gelu_f(gt*o[tid]     + (1.f-gt)*x[tid]);
  float v1 = gelu_f(gt*o[tid+128] + (1.f-gt)*x[tid+128]);
  float v2 = gelu_f(gt*o[tid+256] + (1.f-gt)*x[tid+256]);
  int lane = tid & 63, wid = tid >> 6;
  float s = wsum64(v0+v1+v2);
  if (lane==0) red[wid] = s;
  __syncthreads();
  float mean = (red[0]+red[1]) * (1.0f/384.0f);
  __syncthreads();
  float d0=v0-mean, d1=v1-mean, d2=v2-mean;
  float q = wsum64(d0*d0+d1*d1+d2*d2);
  if (lane==0) red[wid] = q;
  __syncthreads();
  float var = (red[0]+red[1]) * (1.0f/384.0f);
  float rs = 1.0f/sqrtf(var + 1e-5f);
  const float* g = lng + (size_t)t*384;
  const float* b = lnb + (size_t)t*384;
  x[tid]     = d0*rs*g[tid]     + b[tid];
  x[tid+128] = d1*rs*g[tid+128] + b[tid+128];
  x[tid+256] = d2*rs*g[tid+256] + b[tid+256];
}

__global__ __launch_bounds__(128) void k_lnrow(
    const float* __restrict__ X, float* __restrict__ Y,
    const float* __restrict__ g, const float* __restrict__ b, int act)
{
  __shared__ float red[2];
  int row = blockIdx.x, tid = threadIdx.x;
  const float* x = X + (size_t)row*384;
  float* y = Y + (size_t)row*384;
  float v0 = x[tid], v1 = x[tid+128], v2 = x[tid+256];
  int lane = tid & 63, wid = tid >> 6;
  float s = wsum64(v0+v1+v2);
  if (lane==0) red[wid] = s;
  __syncthreads();
  float mean = (red[0]+red[1]) * (1.0f/384.0f);
  __syncthreads();
  float d0=v0-mean, d1=v1-mean, d2=v2-mean;
  float q = wsum64(d0*d0+d1*d1+d2*d2);
  if (lane==0) red[wid] = q;
  __syncthreads();
  float var = (red[0]+red[1]) * (1.0f/384.0f);
  float rs = 1.0f/sqrtf(var + 1e-5f);
  float u0 = d0*rs*g[tid]     + b[tid];
  float u1 = d1*rs*g[tid+128] + b[tid+128];
  float u2 = d2*rs*g[tid+256] + b[tid+256];
  if (act==1){ u0=fmaxf(u0,0.f); u1=fmaxf(u1,0.f); u2=fmaxf(u2,0.f); }
  else       { u0=gelu_f(u0); u1=gelu_f(u1); u2=gelu_f(u2); }
  y[tid] = u0; y[tid+128] = u1; y[tid+256] = u2;
}

/* ---------------- reductions / misc ---------------- */

__global__ __launch_bounds__(256) void k_sumsq(const float* __restrict__ x, int n, float* out){
  __shared__ float red[4];
  float s = 0.f;
  for (int i = blockIdx.x*256 + threadIdx.x; i < n; i += gridDim.x*256){ float v=x[i]; s += v*v; }
  s = wsum64(s);
  int lane = threadIdx.x & 63, wid = threadIdx.x >> 6;
  if (lane==0) red[wid] = s;
  __syncthreads();
  if (threadIdx.x==0) atomicAdd(out, red[0]+red[1]+red[2]+red[3]);
}

__global__ void k_colsum(const float* __restrict__ A, int R, int C, float scale,
                         float* __restrict__ out){
  int col = blockIdx.x*256 + threadIdx.x;
  if (col >= C) return;
  int nchunk = gridDim.y;
  int chunk = (R + nchunk - 1)/nchunk;
  int r0 = blockIdx.y*chunk, r1 = min(R, r0+chunk);
  float s = 0.f;
  for (int r=r0; r<r1; r++) s += A[(size_t)r*C + col];
  atomicAdd(&out[col], s*scale);
}

__global__ __launch_bounds__(256) void k_dnm(const float* __restrict__ QB,
    const float* __restrict__ KSUM, const float* __restrict__ sqsk, float* __restrict__ DNM){
  int wv = blockIdx.x*4 + (threadIdx.x>>6);
  int n = wv >> 2, h = wv & 3;
  int lane = threadIdx.x & 63;
  const float* q = QB + (size_t)n*1536 + h*384;
  const float* ks = KSUM + h*384;
  float p = 0.f;
  #pragma unroll
  for (int d=lane; d<384; d+=64) p += q[d]*ks[d];
  p = wsum64(p);
  if (lane==0) DNM[n*4+h] = p * (1.0f/sqrtf(sqsk[0]*sqsk[1])) + 2048.0f;
}

__global__ void k_zcomb(const float* __restrict__ ZN, const float* __restrict__ VB_,
                        const float* __restrict__ DNM_, const float* __restrict__ sqsk,
                        float* __restrict__ XG_,
                        const float* __restrict__ bng, const float* __restrict__ bnb){
  int i = blockIdx.x*256 + threadIdx.x;
  if (i >= 2048*384) return;
  int n = i / 384, c = i - n*384;
  float inv_s = 1.0f/sqrtf(sqsk[0]*sqsk[1]);
  float zm = 0.f;
  #pragma unroll
  for (int h=0;h<4;h++){
    float num = ZN[(size_t)n*1536 + h*384 + c]*inv_s + 2048.0f*VB_[(size_t)n*1536 + h*384 + c];
    zm += num / DNM_[n*4+h];
  }
  zm *= 0.25f;
  float y = 0.5f*zm + 0.5f*XG_[i];
  y = y * (bng[c] * BNCONST) + bnb[c];
  XG_[i] = fmaxf(y, 0.f);
}

/* ---------------- parallel small GEMV: partials + finalize ---------------- */

__global__ __launch_bounds__(256) void k_gemv_ks(
    const float* __restrict__ in, int K, const float* __restrict__ W, int ldw,
    float* __restrict__ tmp, int N)
{
  int c = blockIdx.x*64 + (threadIdx.x & 63);
  int w = threadIdx.x >> 6;
  int kch = blockIdx.y, nk = gridDim.y;
  int k0 = (int)(((long long)K * kch) / nk);
  int k1 = (int)(((long long)K * (kch+1)) / nk);
  float s = 0.f;
  if (c < N){
    for (int k = k0 + w; k < k1; k += 4)
      s += in[k] * W[(size_t)k*ldw + c];
  }
  __shared__ float red[4][64];
  red[w][threadIdx.x & 63] = s;
  __syncthreads();
  if (w == 0 && c < N){
    int l = threadIdx.x & 63;
    tmp[(size_t)kch*N + c] = red[0][l] + red[1][l] + red[2][l] + red[3][l];
  }
}

__global__ void k_gemv_fin(const float* __restrict__ tmp, int nk,
                           const float* __restrict__ b, float* __restrict__ out, int N, int act){
  int c = blockIdx.x*256 + threadIdx.x;
  if (c >= N) return;
  float v = 0.f;
  for (int i = 0; i < nk; i++) v += tmp[(size_t)i*N + c];
  v += b[c];
  if (act==1) v = fmaxf(v, 0.f);
  out[c] = v;
}

__global__ __launch_bounds__(256) void k_rowdot(const float* __restrict__ A, int lda, int K,
    const float* __restrict__ w, const float* __restrict__ b, float* __restrict__ out, int M){
  int r = blockIdx.x*4 + (threadIdx.x>>6);
  if (r >= M) return;
  int lane = threadIdx.x & 63;
  const float* a = A + (size_t)r*lda;
  float p = 0.f;
  for (int k = lane; k < K; k += 64) p += a[k]*w[k];
  p = wsum64(p);
  if (lane==0) out[r] = sigm(p + b[0]);
}

__global__ __launch_bounds__(64) void k_final(const float* __restrict__ z2,
    const float* __restrict__ w, const float* __restrict__ b, float* __restrict__ out){
  int lane = threadIdx.x;
  float p = 0.f;
  for (int k = lane; k < 192; k += 64) p += z2[k]*w[k];
  p = wsum64(p);
  if (lane==0){
    float l = p + b[0];
    out[0] = l;
    out[1] = sigm(l);
  }
}

/* ================================================================ */

extern "C" void kernel_launch(void* const* d_in, const int* in_sizes, int n_in,
                              void* d_out, int out_size, void* d_ws, size_t ws_size,
                              hipStream_t stream)
{
  const float* xin[5] = {(const float*)d_in[0], (const float*)d_in[1], (const float*)d_in[2],
                         (const float*)d_in[3], (const float*)d_in[4]};
  const float* Wkqv=(const float*)d_in[5];  const float* bkqv=(const float*)d_in[6];
  const float* Wout=(const float*)d_in[7];  const float* bout=(const float*)d_in[8];
  const float* krel=(const float*)d_in[9];  const float* vrel=(const float*)d_in[10];
  const float* prel=(const float*)d_in[11]; const float* skp =(const float*)d_in[12];
  const float* lng =(const float*)d_in[13]; const float* lnb =(const float*)d_in[14];
  const float* sp_W=(const float*)d_in[15]; const float* sp_b=(const float*)d_in[16];
  const float* sp_lng=(const float*)d_in[17]; const float* sp_lnb=(const float*)d_in[18];
  const float* fc0_W=(const float*)d_in[19]; const float* fc0_b=(const float*)d_in[20];
  const float* bn_g=(const float*)d_in[21]; const float* bn_b=(const float*)d_in[22];
  const float* tq_W=(const float*)d_in[23]; const float* tq_b=(const float*)d_in[24];
  const float* tk_W=(const float*)d_in[25]; const float* tk_b=(const float*)d_in[26];
  const float* tv_W=(const float*)d_in[27]; const float* tv_b=(const float*)d_in[28];
  const float* mWqkv=(const float*)d_in[29]; const float* mbqkv=(const float*)d_in[30];
  const float* mWo=(const float*)d_in[31];  const float* mbo=(const float*)d_in[32];
  const float* c1W=(const float*)d_in[33];  const float* c1b=(const float*)d_in[34];
  const float* c2W=(const float*)d_in[35];  const float* c2b=(const float*)d_in[36];
  const float* opW=(const float*)d_in[37];  const float* opb=(const float*)d_in[38];
  const float* as1W=(const float*)d_in[39]; const float* as1b=(const float*)d_in[40];
  const float* as2W=(const float*)d_in[41]; const float* as2b=(const float*)d_in[42];
  const float* sc1W=(const float*)d_in[43]; const float* sc1b=(const float*)d_in[44];
  const float* sc2W=(const float*)d_in[45]; const float* sc2b=(const float*)d_in[46];
  const float* cl1W=(const float*)d_in[47]; const float* cl1b=(const float*)d_in[48];
  const float* cllng=(const float*)d_in[49]; const float* cllnb=(const float*)d_in[50];
  const float* cl2W=(const float*)d_in[51]; const float* cl2b=(const float*)d_in[52];
  const float* cl3W=(const float*)d_in[53]; const float* cl3b=(const float*)d_in[54];
  const float* tpW=(const float*)d_in[55];  const float* tpb=(const float*)d_in[56];
  const int* e_src=(const int*)d_in[57];  const int* e_dst=(const int*)d_in[58];
  float* out = (float*)d_out;

  /* workspace arena */
  char* ws = (char*)d_ws;
  size_t off_b = 0;
  auto alloc = [&](size_t bytes)->char*{
    char* r = ws + off_b;
    off_b = (off_b + bytes + 255) & ~(size_t)255;
    return r;
  };
  float* X    = (float*)alloc((size_t)8192*384*4);
  float* KQV  = (float*)alloc((size_t)8192*1152*4);
  float* KE   = (float*)alloc((size_t)14336*384*4);
  float* VE   = (float*)alloc((size_t)14336*384*4);
  float* AGG  = (float*)alloc((size_t)8192*384*4);
  float* EA   = (float*)alloc((size_t)NEDGE*4*4);
  int* edg    = (int*)alloc((size_t)NEDGE*4);
  int* esr    = (int*)alloc((size_t)NEDGE*4);
  int* erl    = (int*)alloc((size_t)NEDGE*4);
  int* csr    = (int*)alloc((size_t)NEDGE*4);
  int* cnt    = (int*)alloc(8192*4);
  int* cnt2   = (int*)alloc(8192*4);
  int* coff   = (int*)alloc(8193*4);
  unsigned* EMX = (unsigned*)alloc(8192*4*4);
  float* EDEN = (float*)alloc(8192*4*4);
  float* SM   = (float*)alloc(65536);
  float* GT   = (float*)alloc(20*384*4);
  if (off_b > ws_size) return;

  float* SQSK = SM;
  float* TRAJSUM = SM + 8;
  float* DECAYSUM = SM + 392;
  float* TEMB = SM + 600;
  float* AIPOOL = SM + 984;
  float* BCTXV = SM + 1368;
  float* SDELT = SM + 1752;
  float* SDIN = SM + 2048;
  float* T1   = SM + 2816;
  float* Z1   = SM + 3200;
  float* Zb   = SM + 3584;
  float* Z2   = SM + 3968;
  float* KSUM = SM + 4224;
  float* DNM  = SM + 6144;

  float* QB = KQV;
  float* KB = KQV + (size_t)2048*1536;
  float* VB = KQV + (size_t)2*2048*1536;
  float* MQKV = KQV;
  float* AO = KQV + (size_t)2*2048*1536;
  float* ZNUM = KE;
  float* OWT = KE;
  float* OPART = KE;                       /* flash partials: <= 4*4*2048*96 */
  float* MLBUF = KE + (size_t)3200000;     /* <= 65536 floats */
  float* IMC = KE;                         /* conv im2col 2048x1152 */
  float* WT  = KE + (size_t)2400000;       /* conv weight^T <= 1152*384 */
  float* HS = VE;
  float* XG = VE + (size_t)2048*384;
  float* HM = VE + (size_t)2*2048*384;
  float* C1O = VE + (size_t)3*2048*384;
  float* TRAJ = VE + (size_t)4*2048*384;
  float* AICTX = VE + (size_t)5*2048*384;
  float* C2O = VE + (size_t)6*2048*384;
  float* TMPA = AGG;
  float* CB = AGG;
  float* PT = AGG + (size_t)2048*768;
  float* KVS = AGG + (size_t)2048*1152;

  dim3 B256(256);
  auto gemm = [&](const float* A, int lda, const float* Bw, int ldb, const float* bias,
                  const float* cs, const float* csh, float kmul,
                  float* C, int ldc, int M, int N, int K, int act, int agelu){
    dim3 g((N+63)/64, (M+63)/64);
    gemm_f<<<g, B256, 0, stream>>>(A, lda, Bw, ldb, bias, cs, csh, kmul, C, ldc, M, N, K, act, agelu);
  };
  auto gemv = [&](const float* in, int K, const float* W, int ldw, const float* b,
                  float* o, int N, int act){
    int nk = (K + 79) / 80; if (nk > 20) nk = 20; if (nk < 1) nk = 1;
    k_gemv_ks<<<dim3((N+63)/64, nk), B256, 0, stream>>>(in, K, W, ldw, GT, N);
    k_gemv_fin<<<dim3((N+255)/256), B256, 0, stream>>>(GT, nk, b, o, N, act);
  };

  /* ---- edge CSR ---- */
  hipMemsetAsync(cnt, 0, 8192*4, stream);
  hipMemsetAsync(cnt2, 0, 8192*4, stream);
  k_edge_pre<<<dim3(NEDGE/256), B256, 0, stream>>>(e_src, e_dst, edg, esr, erl, cnt);
  k_scan<<<dim3(1), dim3(1024), 0, stream>>>(cnt, coff);
  k_scatter<<<dim3(NEDGE/256), B256, 0, stream>>>(edg, coff, cnt2, csr);

  /* ---- inputs -> X ---- */
  for (int t=0;t<5;t++)
    hipMemcpyAsync(X + (size_t)h_OFFS[t]*384, xin[t], (size_t)h_NT[t]*384*4,
                   hipMemcpyDeviceToDevice, stream);

  /* ---- HGT layers ---- */
  for (int l=0;l<2;l++){
    /* combined 5-type KQV projection: one 64x128-tile launch, per-tile type select */
    gemm128<<<dim3(9, 128), B256, 0, stream>>>(
        X, 384, 0,
        Wkqv + (size_t)l*5*442368, 1152, 442368,
        bkqv + (size_t)l*5*1152, 1152,
        KQV, 1152, 0, 8192, 1152, 384, 0, 0, 1 /*tsel*/,
        nullptr, nullptr, nullptr, nullptr);
    gemm_rel<<<dim3(2,32,64), B256, 0, stream>>>(
        KQV, krel + (size_t)l*294912, vrel + (size_t)l*294912, KE, VE);
    k_escore<<<dim3(NEDGE/4), B256, 0, stream>>>(KQV, KE, edg, esr, erl, prel + (size_t)l*32, EA);
    hipMemsetAsync(EMX, 0, 8192*4*4, stream);
    hipMemsetAsync(EDEN, 0, 8192*4*4, stream);
    k_segmax<<<dim3(NEDGE*4/256), B256, 0, stream>>>(EA, edg, EMX);
    k_expsum<<<dim3(NEDGE*4/256), B256, 0, stream>>>(EA, edg, EMX, EDEN);
    k_agg<<<dim3(NTOT), dim3(128), 0, stream>>>(EA, VE, EDEN, csr, coff, esr, AGG);
    /* combined 5-type Wout projection (gelu on A) */
    gemm128<<<dim3(3, 128), B256, 0, stream>>>(
        AGG, 384, 0,
        Wout + (size_t)l*5*147456, 384, 147456,
        bout + (size_t)l*5*384, 384,
        OWT, 384, 0, 8192, 384, 384, 0, 1 /*agelu*/, 1 /*tsel*/,
        nullptr, nullptr, nullptr, nullptr);
    k_gateln<<<dim3(NTOT), dim3(128), 0, stream>>>(OWT, X, skp + l*5, lng, lnb);
  }

  const float* user_h   = X;
  const float* ai_h     = X + (size_t)2048*384;
  const float* stance_h = X + (size_t)4096*384;
  const float* belief_h = X + (size_t)7168*384;

  /* ---- hs, xg ---- */
  gemm(stance_h, 384, sp_W, 384, sp_b, nullptr, nullptr, 1.f, TMPA, 384, 2048, 384, 384, 0, 0);
  k_lnrow<<<dim3(2048), dim3(128), 0, stream>>>(TMPA, HS, sp_lng, sp_lnb, 0 /*gelu*/);
  gemm(HS, 384, fc0_W, 384, fc0_b, bn_g, bn_b, BNCONST, XG, 384, 2048, 384, 384, 1 /*relu*/, 0);

  /* ---- linear-attention blocks ---- */
  for (int i=0;i<2;i++){
    /* q/k/v projections batched into one launch: z selects weight/bias pointer,
       C strided (QB,KB,VB contiguous in arena) */
    gemm128<<<dim3(12,32,3), B256, 0, stream>>>(
        XG, 384, 0,
        tq_W + (size_t)i*589824, 1536, 0,
        tq_b + (size_t)i*1536, 0,
        QB, 1536, 2048*1536,
        2048, 1536, 384, 0, 0, 0,
        tk_W + (size_t)i*589824, tv_W + (size_t)i*589824,
        tk_b + (size_t)i*1536, tv_b + (size_t)i*1536);
    hipMemsetAsync(SQSK, 0, 8, stream);
    k_sumsq<<<dim3(512), B256, 0, stream>>>(QB, 2048*1536, SQSK);
    k_sumsq<<<dim3(512), B256, 0, stream>>>(KB, 2048*1536, SQSK+1);
    hipMemsetAsync(KSUM, 0, 1536*4, stream);
    k_colsum<<<dim3(6,8), B256, 0, stream>>>(KB, 2048, 1536, 1.0f, KSUM);
    k_dnm<<<dim3(2048), B256, 0, stream>>>(QB, KSUM, SQSK, DNM);
    hipMemsetAsync(KVS, 0, (size_t)4*147456*4, stream);
    gemm_atb_ks<<<dim3(6,6,32), B256, 0, stream>>>(KB, 1536, VB, 1536, KVS, 384,
        384, 384, 2048, 384, 384, 147456, 8);
    /* 4-head ZNUM batched via grid.z */
    gemm128<<<dim3(3,32,4), B256, 0, stream>>>(
        QB, 1536, 384, KVS, 384, 147456,
        nullptr, 0, ZNUM, 1536, 384, 2048, 384, 384, 0, 0, 0,
        nullptr, nullptr, nullptr, nullptr);
    k_zcomb<<<dim3(3072), B256, 0, stream>>>(ZNUM, VB, DNM, SQSK, XG,
        bn_g + (size_t)(i+1)*384, bn_b + (size_t)(i+1)*384);
  }

  /* ---- h_mixed ---- */
  k_mix<<<dim3(3072), B256, 0, stream>>>(HS, XG, HM, 2048*384, 0.7f, 0.3f);

  /* ---- MHA helper (flash) ---- */
  auto run_mha = [&](const float* qin, int nq, const float* kvin, int nkv, int mi, float* OUT){
    const float* Wq = mWqkv + (size_t)mi*442368;
    const float* bq = mbqkv + (size_t)mi*1152;
    gemm(qin, 384, Wq, 1152, bq, nullptr, nullptr, 1.f, MQKV, 1152, nq, 384, 384, 0, 0);
    gemm(kvin, 384, Wq + 384, 1152, bq + 384, nullptr, nullptr, 1.f, MQKV + 384, 1152, nkv, 768, 384, 0, 0);
    int nch = nkv / 512;
    fa_kernel<<<dim3(nq/64, 4, nch), B256, 0, stream>>>(MQKV, nq, OPART, MLBUF);
    k_famerge<<<dim3((4*nq*96 + 255)/256), B256, 0, stream>>>(OPART, MLBUF, AO, nq, nch);
    gemm(AO, 384, mWo + (size_t)mi*147456, 384, mbo + (size_t)mi*384,
         nullptr, nullptr, 1.f, OUT, 384, nq, 384, 384, 0, 0);
  };

  /* ---- traj ---- */
  run_mha(HM, 2048, HM, 2048, 1, TRAJ);
  hipMemsetAsync(TRAJSUM, 0, 576*4, stream);
  k_colsum<<<dim3(2,8), B256, 0, stream>>>(TRAJ, 2048, 384, 1.0f/2048.0f, TRAJSUM);

  /* ---- conv path (im2col + GEMM, gelu epilogue) ---- */
  k_im2col<<<dim3(2048*1152/256), B256, 0, stream>>>(HM, IMC);
  k_wtr<<<dim3((384*1152+255)/256), B256, 0, stream>>>(c1W, WT, 384);
  gemm(IMC, 1152, WT, 384, c1b, nullptr, nullptr, 1.f, C1O, 384, 2048, 384, 1152, 2 /*gelu*/, 0);
  k_im2col<<<dim3(2048*1152/256), B256, 0, stream>>>(C1O, IMC);
  k_wtr<<<dim3((192*1152+255)/256), B256, 0, stream>>>(c2W, WT, 192);
  gemm(IMC, 1152, WT, 192, c2b, nullptr, nullptr, 1.f, C2O, 192, 2048, 192, 1152, 2 /*gelu*/, 0);
  k_colsum<<<dim3(1,8), B256, 0, stream>>>(C2O, 2048, 192, 1.0f/2048.0f, DECAYSUM);

  /* ---- traj_emb ---- */
  gemv(TRAJSUM, 576, opW, 384, opb, TEMB, 384, 0);

  /* ---- ai_ctx ---- */
  run_mha(ai_h, 2048, user_h, 2048, 0, AICTX);
  hipMemsetAsync(AIPOOL, 0, 384*4, stream);
  k_colsum<<<dim3(2,8), B256, 0, stream>>>(AICTX, 2048, 384, 1.0f/2048.0f, AIPOOL);

  /* ---- pscores ---- */
  k_comb<<<dim3(6144), B256, 0, stream>>>(ai_h, user_h, CB);
  gemm(CB, 768, as1W, 384, as1b, nullptr, nullptr, 1.f, PT, 384, 2048, 384, 768, 1, 0);
  k_rowdot<<<dim3(512), B256, 0, stream>>>(PT, 384, 384, as2W, as2b, out + 2 + 2048, 2048);

  /* ---- bctx ---- */
  run_mha(ai_h, 2048, belief_h, 1024, 2, TRAJ);
  hipMemsetAsync(BCTXV, 0, 384*4, stream);
  k_colsum<<<dim3(2,8), B256, 0, stream>>>(TRAJ, 2048, 384, 1.0f/2048.0f, BCTXV);

  /* ---- stance delta ---- */
  hipMemcpyAsync(SDIN, stance_h, 384*4, hipMemcpyDeviceToDevice, stream);
  hipMemcpyAsync(SDIN + 384, stance_h + (size_t)2047*384, 384*4, hipMemcpyDeviceToDevice, stream);
  gemv(SDIN, 768, sc1W, 384, sc1b, T1, 384, 1);
  gemv(T1, 384, sc2W, 192, sc2b, SDELT, 192, 0);

  /* ---- classifier ---- */
  gemv(TEMB, 1344, cl1W, 384, cl1b, Z1, 384, 0);
  k_lnrow<<<dim3(1), dim3(128), 0, stream>>>(Z1, Zb, cllng, cllnb, 1 /*relu*/);
  gemv(Zb, 384, cl2W, 192, cl2b, Z2, 192, 1);
  k_final<<<dim3(1), dim3(64), 0, stream>>>(Z2, cl3W, cl3b, out);

  /* ---- per_turn ---- */
  k_rowdot<<<dim3(512), B256, 0, stream>>>(AICTX, 384, 384, tpW, tpb, out + 2, 2048);
}

// Round 9
// 2858.852 us; speedup vs baseline: 1.0519x; 1.0031x over previous
//
#include <hip/hip_runtime.h>
#include <hip/hip_bf16.h>

#define NEDGE 229376
#define NTOT  8192
#define BNCONST 0.9999950000374997f   /* 1/sqrt(1+1e-5) */
#define ISQ96   0.10206207261596575f  /* 1/sqrt(96) */

__constant__ int c_NT[5]     = {2048,2048,2048,1024,1024};
__constant__ int c_OFFS[5]   = {0,2048,4096,6144,7168};
__constant__ int c_ESRC[8]   = {0,1,1,2,0,3,1,4};
__constant__ int c_EDST[8]   = {1,0,2,2,3,1,4,2};
__constant__ int c_EOFF[9]   = {0,32768,65536,98304,131072,147456,180224,196608,229376};
__constant__ int c_RELROW[8] = {0,2048,4096,6144,8192,10240,11264,13312};

static const int h_NT[5]   = {2048,2048,2048,1024,1024};
static const int h_OFFS[5] = {0,2048,4096,6144,7168};

__device__ inline float gelu_f(float x){ return 0.5f*x*(1.0f+erff(x*0.70710678118654752f)); }
__device__ inline float sigm(float x){ return 1.0f/(1.0f+expf(-x)); }
__device__ inline float wsum64(float v){
  #pragma unroll
  for (int s=32;s>0;s>>=1) v += __shfl_xor(v, s, 64);
  return v;
}
__device__ inline unsigned encf(float f){
  unsigned b = __float_as_uint(f);
  return (b & 0x80000000u) ? ~b : (b | 0x80000000u);
}
__device__ inline float decf(unsigned u){
  unsigned b = (u & 0x80000000u) ? (u & 0x7FFFFFFFu) : ~u;
  return __uint_as_float(b);
}
__device__ inline int row_type(int row){
  return (row<2048)?0:((row<4096)?1:((row<6144)?2:((row<7168)?3:4)));
}
/* reduce across the 16-lane row group (lanes ty*16..+15) */
__device__ inline float rgmax(float v){
  v = fmaxf(v, __shfl_xor(v, 1, 64));
  v = fmaxf(v, __shfl_xor(v, 2, 64));
  v = fmaxf(v, __shfl_xor(v, 4, 64));
  v = fmaxf(v, __shfl_xor(v, 8, 64));
  return v;
}
__device__ inline float rgsum(float v){
  v += __shfl_xor(v, 1, 64);
  v += __shfl_xor(v, 2, 64);
  v += __shfl_xor(v, 4, 64);
  v += __shfl_xor(v, 8, 64);
  return v;
}

/* ---------------- simple utility kernels ---------------- */

__global__ void k_mix(const float* __restrict__ a, const float* __restrict__ b,
                      float* __restrict__ c, int n, float fa, float fb){
  int i = blockIdx.x*256 + threadIdx.x;
  if (i < n) c[i] = fa*a[i] + fb*b[i];
}

__global__ void k_comb(const float* __restrict__ ai, const float* __restrict__ user,
                       float* __restrict__ cb){
  int i = blockIdx.x*256 + threadIdx.x;
  if (i >= 2048*768) return;
  int n = i / 768, c = i - n*768;
  cb[i] = (c < 384) ? ai[n*384 + c] : user[n*384 + (c-384)];
}

/* ---------------- edge preprocessing (CSR by destination) ---------------- */

__global__ void k_edge_pre(const int* __restrict__ esrc, const int* __restrict__ edst,
                           int* edg, int* esr, int* erl, int* cnt){
  int e = blockIdx.x*256 + threadIdx.x;
  if (e >= NEDGE) return;
  int r = 0;
  #pragma unroll
  for (int q=1;q<8;q++) if (e >= c_EOFF[q]) r = q;
  int dg = c_OFFS[c_EDST[r]] + edst[e];
  edg[e] = dg;
  esr[e] = c_RELROW[r] + esrc[e];
  erl[e] = r;
  atomicAdd(&cnt[dg], 1);
}

__global__ __launch_bounds__(1024) void k_scan(const int* __restrict__ cnt, int* __restrict__ off){
  __shared__ int sh[1024];
  int tid = threadIdx.x;
  int base = tid*8;
  int loc[8]; int run = 0;
  #pragma unroll
  for (int i=0;i<8;i++){ loc[i] = run; run += cnt[base+i]; }
  sh[tid] = run;
  __syncthreads();
  for (int d=1; d<1024; d<<=1){
    int v = (tid >= d) ? sh[tid-d] : 0;
    __syncthreads();
    sh[tid] += v;
    __syncthreads();
  }
  int pre = (tid==0) ? 0 : sh[tid-1];
  #pragma unroll
  for (int i=0;i<8;i++) off[base+i] = pre + loc[i];
  if (tid==1023) off[8192] = sh[1023];
}

__global__ void k_scatter(const int* __restrict__ edg, const int* __restrict__ off,
                          int* cnt2, int* csr){
  int e = blockIdx.x*256 + threadIdx.x;
  if (e >= NEDGE) return;
  int dg = edg[e];
  int pos = off[dg] + atomicAdd(&cnt2[dg], 1);
  csr[pos] = e;
}

/* ------- tiled GEMMs: 64x64 tile, 4x4 microtile, double-buffered + float4 stage ------- */

__global__ __launch_bounds__(256) void gemm_f(
    const float* __restrict__ A, int lda, const float* __restrict__ B, int ldb,
    const float* __restrict__ bias, const float* __restrict__ cs, const float* __restrict__ csh,
    float kmul, float* __restrict__ C, int ldc, int M, int N, int K, int act, int agelu)
{
  __shared__ float As[2][16][68];
  __shared__ float Bs[2][16][68];
  int tid = threadIdx.x;
  int tx = tid & 15, ty = tid >> 4;
  int am = tid >> 2, ak = (tid & 3) * 4;
  int bk = tid >> 4, bn = (tid & 15) * 4;
  int m0 = blockIdx.y * 64, n0 = blockIdx.x * 64;
  int gmA = m0 + am;
  int gnB = n0 + bn;
  int ntiles = K >> 4;
  float4 ra, rb;
  float acc[4][4] = {};

  auto fetch = [&](int kk){
    if (gmA < M){
      ra = *reinterpret_cast<const float4*>(&A[(size_t)gmA*lda + kk + ak]);
      if (agelu){ ra.x=gelu_f(ra.x); ra.y=gelu_f(ra.y); ra.z=gelu_f(ra.z); ra.w=gelu_f(ra.w); }
    } else ra = make_float4(0.f,0.f,0.f,0.f);
    if (gnB + 3 < N){
      rb = *reinterpret_cast<const float4*>(&B[(size_t)(kk + bk)*ldb + gnB]);
    } else {
      rb.x = (gnB   < N) ? B[(size_t)(kk + bk)*ldb + gnB  ] : 0.f;
      rb.y = (gnB+1 < N) ? B[(size_t)(kk + bk)*ldb + gnB+1] : 0.f;
      rb.z = (gnB+2 < N) ? B[(size_t)(kk + bk)*ldb + gnB+2] : 0.f;
      rb.w = (gnB+3 < N) ? B[(size_t)(kk + bk)*ldb + gnB+3] : 0.f;
    }
  };
  auto stage = [&](int b){
    As[b][ak  ][am] = ra.x;
    As[b][ak+1][am] = ra.y;
    As[b][ak+2][am] = ra.z;
    As[b][ak+3][am] = ra.w;
    *reinterpret_cast<float4*>(&Bs[b][bk][bn]) = rb;
  };

  fetch(0);
  stage(0);
  __syncthreads();
  for (int t = 0; t < ntiles; t++){
    int cur = t & 1;
    if (t + 1 < ntiles) fetch((t+1) << 4);
    #pragma unroll
    for (int k = 0; k < 16; k++) {
      float4 a4 = *reinterpret_cast<const float4*>(&As[cur][k][ty*4]);
      float4 b4 = *reinterpret_cast<const float4*>(&Bs[cur][k][tx*4]);
      float a[4] = {a4.x, a4.y, a4.z, a4.w};
      float b[4] = {b4.x, b4.y, b4.z, b4.w};
      #pragma unroll
      for (int i=0;i<4;i++)
        #pragma unroll
        for (int j=0;j<4;j++) acc[i][j] += a[i]*b[j];
    }
    if (t + 1 < ntiles) stage(cur ^ 1);
    __syncthreads();
  }
  #pragma unroll
  for (int i=0;i<4;i++){
    int gm = m0 + ty*4 + i; if (gm >= M) continue;
    #pragma unroll
    for (int j=0;j<4;j++){
      int gn = n0 + tx*4 + j; if (gn >= N) continue;
      float v = acc[i][j];
      if (bias) v += bias[gn];
      float s = kmul;
      if (cs) s *= cs[gn];
      v *= s;
      if (csh) v += csh[gn];
      if (act==1) v = fmaxf(v, 0.f);
      else if (act==2) v = gelu_f(v);
      C[(size_t)gm*ldc + gn] = v;
    }
  }
}

/* ------- big GEMM v3: 64x128 tile, 4x8 SPLIT microtile, SINGLE-buffered LDS.
   Natural VGPR ~100-120 (plain launch_bounds(256) — min-waves arg spills on
   this toolchain, R3/R4), 12.8KB LDS -> 4 blocks/CU, prefetch-into-regs
   hides global latency. Verified R5: 3388->2911 on KQV/Wout/qkv/ZNUM sites.
   Only use at >=~200 blocks (R6: 96-block launches regressed). */
__global__ __launch_bounds__(256) void gemm128(
    const float* __restrict__ A, int lda, int sAz,
    const float* __restrict__ B, int ldb, int sBz,
    const float* __restrict__ bias, int sbz,
    float* __restrict__ C, int ldc, int sCz,
    int M, int N, int K, int act, int agelu, int tsel,
    const float* __restrict__ Bp1, const float* __restrict__ Bp2,
    const float* __restrict__ biasp1, const float* __restrict__ biasp2)
{
  __shared__ float As[16][68];
  __shared__ float Bs[16][132];
  int tid = threadIdx.x;
  int tx = tid & 15, ty = tid >> 4;
  int am = tid >> 2, ak = (tid & 3) * 4;
  int bk = tid >> 4, bn = (tid & 15) * 4;

  /* XCD-chunked bijective swizzle of the xy-plane block id (m204 formula) */
  int nxy = gridDim.x * gridDim.y;
  int orig = blockIdx.y * gridDim.x + blockIdx.x;
  int q = nxy >> 3, r = nxy & 7;
  int xcd = orig & 7, rest = orig >> 3;
  int wg = ((xcd < r) ? xcd*(q+1) : r*(q+1) + (xcd - r)*q) + rest;
  int bx = wg % gridDim.x, by = wg / gridDim.x;
  int m0 = by * 64, n0 = bx * 128;

  int z = blockIdx.z;
  const float* Ab = A + (size_t)z * sAz;
  const float* Bb;
  const float* bb;
  if (Bp1){
    Bb = (z == 0) ? B : ((z == 1) ? Bp1 : Bp2);
    bb = (z == 0) ? bias : ((z == 1) ? biasp1 : biasp2);
  } else {
    Bb = B + (size_t)z * sBz;
    bb = bias ? (bias + (size_t)z * sbz) : nullptr;
  }
  float* Cb = C + (size_t)z * sCz;
  if (tsel){
    int t = row_type(m0);
    Bb = B + (size_t)t * sBz;
    bb = bias ? (bias + (size_t)t * sbz) : nullptr;
  }
  int gmA = m0 + am, gnB = n0 + bn;
  int ntiles = K >> 4;
  float4 ra, rb0, rb1;
  float acc[4][8] = {};

  auto fetch = [&](int kk){
    if (gmA < M){
      ra = *reinterpret_cast<const float4*>(&Ab[(size_t)gmA*lda + kk + ak]);
      if (agelu){
        ra.x=gelu_f(ra.x); ra.y=gelu_f(ra.y); ra.z=gelu_f(ra.z); ra.w=gelu_f(ra.w);
      }
    } else {
      ra = make_float4(0.f,0.f,0.f,0.f);
    }
    if (gnB + 67 < N){
      rb0 = *reinterpret_cast<const float4*>(&Bb[(size_t)(kk + bk)*ldb + gnB]);
      rb1 = *reinterpret_cast<const float4*>(&Bb[(size_t)(kk + bk)*ldb + gnB + 64]);
    } else {
      const float* bp = &Bb[(size_t)(kk + bk)*ldb];
      rb0.x = (gnB    < N) ? bp[gnB   ] : 0.f;
      rb0.y = (gnB+1  < N) ? bp[gnB+ 1] : 0.f;
      rb0.z = (gnB+2  < N) ? bp[gnB+ 2] : 0.f;
      rb0.w = (gnB+3  < N) ? bp[gnB+ 3] : 0.f;
      rb1.x = (gnB+64 < N) ? bp[gnB+64] : 0.f;
      rb1.y = (gnB+65 < N) ? bp[gnB+65] : 0.f;
      rb1.z = (gnB+66 < N) ? bp[gnB+66] : 0.f;
      rb1.w = (gnB+67 < N) ? bp[gnB+67] : 0.f;
    }
  };
  auto stage = [&](){
    As[ak  ][am] = ra.x;
    As[ak+1][am] = ra.y;
    As[ak+2][am] = ra.z;
    As[ak+3][am] = ra.w;
    *reinterpret_cast<float4*>(&Bs[bk][bn     ]) = rb0;
    *reinterpret_cast<float4*>(&Bs[bk][bn + 64]) = rb1;
  };

  fetch(0);
  for (int t = 0; t < ntiles; t++){
    if (t > 0) __syncthreads();
    stage();
    __syncthreads();
    if (t + 1 < ntiles) fetch((t+1) << 4);
    #pragma unroll
    for (int k = 0; k < 16; k++) {
      float4 a4 = *reinterpret_cast<const float4*>(&As[k][ty*4]);
      float4 b0 = *reinterpret_cast<const float4*>(&Bs[k][tx*4]);
      float4 b1 = *reinterpret_cast<const float4*>(&Bs[k][64 + tx*4]);
      float a[4] = {a4.x,a4.y,a4.z,a4.w};
      float b[8] = {b0.x,b0.y,b0.z,b0.w,b1.x,b1.y,b1.z,b1.w};
      #pragma unroll
      for (int i=0;i<4;i++)
        #pragma unroll
        for (int j=0;j<8;j++) acc[i][j] += a[i]*b[j];
    }
  }

  bool fullN = (n0 + 127 < N);
  int cb0 = n0 + tx*4, cb1 = n0 + 64 + tx*4;
  #pragma unroll
  for (int i=0;i<4;i++){
    int gm = m0 + ty*4 + i;
    if (gm >= M) continue;
    float v[8];
    #pragma unroll
    for (int jh=0; jh<2; jh++){
      #pragma unroll
      for (int j=0;j<4;j++){
        float x = acc[i][jh*4+j];
        int gn = (jh ? cb1 : cb0) + j;
        if (bb && gn < N) x += bb[gn];
        if (act==1) x = fmaxf(x, 0.f);
        else if (act==2) x = gelu_f(x);
        v[jh*4+j] = x;
      }
    }
    if (fullN){
      *reinterpret_cast<float4*>(&Cb[(size_t)gm*ldc + cb0]) = make_float4(v[0],v[1],v[2],v[3]);
      *reinterpret_cast<float4*>(&Cb[(size_t)gm*ldc + cb1]) = make_float4(v[4],v[5],v[6],v[7]);
    } else {
      #pragma unroll
      for (int jh=0; jh<2; jh++){
        #pragma unroll
        for (int j=0;j<4;j++){
          int gn = (jh ? cb1 : cb0) + j;
          if (gn < N) Cb[(size_t)gm*ldc + gn] = v[jh*4+j];
        }
      }
    }
  }
}

/* batched HGT relation projection as GEMM: z = (r*4+h)*2 + w */
__global__ __launch_bounds__(256) void gemm_rel(
    const float* __restrict__ KQV_, const float* __restrict__ krel_l,
    const float* __restrict__ vrel_l, float* __restrict__ KE_, float* __restrict__ VE_)
{
  int z = blockIdx.z;
  int w = z & 1, h = (z >> 1) & 3, r = z >> 3;
  int s = c_ESRC[r];
  int Ns = c_NT[s];
  int m0 = blockIdx.y * 64;
  if (m0 >= Ns) return;
  int n0 = blockIdx.x * 64;
  const float* A = KQV_ + (size_t)c_OFFS[s]*1152 + (w ? 768 : 0) + h*96;
  const float* B = (w ? vrel_l : krel_l) + (size_t)(r*4 + h)*9216;
  float* C = (w ? VE_ : KE_) + (size_t)c_RELROW[r]*384 + h*96;

  __shared__ float As[2][16][68];
  __shared__ float Bs[2][16][68];
  int tid = threadIdx.x;
  int tx = tid & 15, ty = tid >> 4;
  int am = tid >> 2, ak = (tid & 3) * 4;
  int bk = tid >> 4, bn = (tid & 15) * 4;
  int gmA = m0 + am;
  int gnB = n0 + bn;
  float4 ra, rb;
  float acc[4][4] = {};

  auto fetch = [&](int kk){
    ra = (gmA < Ns) ? *reinterpret_cast<const float4*>(&A[(size_t)gmA*1152 + kk + ak])
                    : make_float4(0.f,0.f,0.f,0.f);
    if (gnB + 3 < 96){
      rb = *reinterpret_cast<const float4*>(&B[(size_t)(kk + bk)*96 + gnB]);
    } else {
      rb.x = (gnB   < 96) ? B[(size_t)(kk + bk)*96 + gnB  ] : 0.f;
      rb.y = (gnB+1 < 96) ? B[(size_t)(kk + bk)*96 + gnB+1] : 0.f;
      rb.z = (gnB+2 < 96) ? B[(size_t)(kk + bk)*96 + gnB+2] : 0.f;
      rb.w = (gnB+3 < 96) ? B[(size_t)(kk + bk)*96 + gnB+3] : 0.f;
    }
  };
  auto stage = [&](int b){
    As[b][ak  ][am] = ra.x;
    As[b][ak+1][am] = ra.y;
    As[b][ak+2][am] = ra.z;
    As[b][ak+3][am] = ra.w;
    *reinterpret_cast<float4*>(&Bs[b][bk][bn]) = rb;
  };

  fetch(0);
  stage(0);
  __syncthreads();
  for (int t = 0; t < 6; t++){
    int cur = t & 1;
    if (t + 1 < 6) fetch((t+1) << 4);
    #pragma unroll
    for (int k = 0; k < 16; k++) {
      float4 a4 = *reinterpret_cast<const float4*>(&As[cur][k][ty*4]);
      float4 b4 = *reinterpret_cast<const float4*>(&Bs[cur][k][tx*4]);
      float a[4] = {a4.x, a4.y, a4.z, a4.w};
      float b[4] = {b4.x, b4.y, b4.z, b4.w};
      #pragma unroll
      for (int i=0;i<4;i++)
        #pragma unroll
        for (int j=0;j<4;j++) acc[i][j] += a[i]*b[j];
    }
    if (t + 1 < 6) stage(cur ^ 1);
    __syncthreads();
  }
  #pragma unroll
  for (int i=0;i<4;i++){
    int gm = m0 + ty*4 + i; if (gm >= Ns) continue;
    #pragma unroll
    for (int j=0;j<4;j++){
      int gn = n0 + tx*4 + j; if (gn >= 96) continue;
      C[(size_t)gm*384 + gn] = acc[i][j];
    }
  }
}

// C[m,n] += sum_l A[l,m]*B[l,n], head-batched + L-split (atomic accumulate).
__global__ __launch_bounds__(256) void gemm_atb_ks(
    const float* __restrict__ A0, int lda, const float* __restrict__ B0, int ldb,
    float* __restrict__ C0, int ldc, int M, int N, int L,
    int hsA, int hsB, int hsC, int nch)
{
  __shared__ float As[2][16][68];
  __shared__ float Bs[2][16][68];
  int h = blockIdx.z / nch, c = blockIdx.z % nch;
  const float* A = A0 + (size_t)h*hsA;
  const float* B = B0 + (size_t)h*hsB;
  float* C = C0 + (size_t)h*hsC;
  int l0 = c*256;
  int tid = threadIdx.x;
  int tx = tid & 15, ty = tid >> 4;
  int sl = tid >> 4, sq = (tid & 15) * 4;
  int m0 = blockIdx.y * 64, n0 = blockIdx.x * 64;
  int gmA = m0 + sq, gnB = n0 + sq;
  int ntiles = 16;
  float4 ra, rb;
  float acc[4][4] = {};

  auto fetch = [&](int ll){
    if (gmA + 3 < M){
      ra = *reinterpret_cast<const float4*>(&A[(size_t)(ll + sl)*lda + gmA]);
    } else {
      ra.x = (gmA   < M) ? A[(size_t)(ll + sl)*lda + gmA  ] : 0.f;
      ra.y = (gmA+1 < M) ? A[(size_t)(ll + sl)*lda + gmA+1] : 0.f;
      ra.z = (gmA+2 < M) ? A[(size_t)(ll + sl)*lda + gmA+2] : 0.f;
      ra.w = (gmA+3 < M) ? A[(size_t)(ll + sl)*lda + gmA+3] : 0.f;
    }
    if (gnB + 3 < N){
      rb = *reinterpret_cast<const float4*>(&B[(size_t)(ll + sl)*ldb + gnB]);
    } else {
      rb.x = (gnB   < N) ? B[(size_t)(ll + sl)*ldb + gnB  ] : 0.f;
      rb.y = (gnB+1 < N) ? B[(size_t)(ll + sl)*ldb + gnB+1] : 0.f;
      rb.z = (gnB+2 < N) ? B[(size_t)(ll + sl)*ldb + gnB+2] : 0.f;
      rb.w = (gnB+3 < N) ? B[(size_t)(ll + sl)*ldb + gnB+3] : 0.f;
    }
  };
  auto stage = [&](int b){
    *reinterpret_cast<float4*>(&As[b][sl][sq]) = ra;
    *reinterpret_cast<float4*>(&Bs[b][sl][sq]) = rb;
  };

  fetch(l0);
  stage(0);
  __syncthreads();
  for (int t = 0; t < ntiles; t++){
    int cur = t & 1;
    if (t + 1 < ntiles) fetch(l0 + ((t+1) << 4));
    #pragma unroll
    for (int l = 0; l < 16; l++) {
      float4 a4 = *reinterpret_cast<const float4*>(&As[cur][l][ty*4]);
      float4 b4 = *reinterpret_cast<const float4*>(&Bs[cur][l][tx*4]);
      float a[4] = {a4.x, a4.y, a4.z, a4.w};
      float b[4] = {b4.x, b4.y, b4.z, b4.w};
      #pragma unroll
      for (int i=0;i<4;i++)
        #pragma unroll
        for (int j=0;j<4;j++) acc[i][j] += a[i]*b[j];
    }
    if (t + 1 < ntiles) stage(cur ^ 1);
    __syncthreads();
  }
  #pragma unroll
  for (int i=0;i<4;i++){
    int gm = m0 + ty*4 + i; if (gm >= M) continue;
    #pragma unroll
    for (int j=0;j<4;j++){
      int gn = n0 + tx*4 + j; if (gn >= N) continue;
      atomicAdd(&C[(size_t)gm*ldc + gn], acc[i][j]);
    }
  }
}

/* ---------------- flash attention v1 (R5-exact): q-tile 64, kv-tile 32 ----------------
   R9: R8's cross-loop register prefetch was demoted to LDS by the compiler
   (LDS 62464->74752, +12KB = the kf/vf state) adding LDS traffic to an
   LDS-BW-bound kernel: 142->165us, VALU 45->37%. Reverted to the R5-exact
   structure: fetch fused into stage, no state held across the compute loop.
   grid (nq/64, 4 heads, nkv/512); MQKV row*1152: Q[0..383] K[384..767] V[768..1151] */
__global__ __launch_bounds__(256) void fa_kernel(
    const float* __restrict__ MQ, int nq, float* __restrict__ OP, float* __restrict__ ML)
{
  __shared__ float Qs[96][68];
  __shared__ float Ksf[96][36];
  __shared__ float Vs[32][104];
  __shared__ float Ps[64][36];
  int tid = threadIdx.x;
  int tx = tid & 15, ty = tid >> 4;
  int q0 = blockIdx.x * 64;
  int h = blockIdx.y;
  int z = blockIdx.z, nch = gridDim.z;
  int kvbase = z * 512;

  /* stage Q tile [k][r] */
  #pragma unroll
  for (int i = 0; i < 6; i++){
    int e = tid + i*256;
    int r = e & 63, kq = (e >> 6) * 4;
    float4 f = *reinterpret_cast<const float4*>(&MQ[(size_t)(q0+r)*1152 + h*96 + kq]);
    Qs[kq  ][r] = f.x;
    Qs[kq+1][r] = f.y;
    Qs[kq+2][r] = f.z;
    Qs[kq+3][r] = f.w;
  }

  float m_i[4], l_i[4], acc[4][6];
  #pragma unroll
  for (int i=0;i<4;i++){
    m_i[i] = -3.0e38f; l_i[i] = 0.f;
    #pragma unroll
    for (int c=0;c<6;c++) acc[i][c] = 0.f;
  }
  int c0 = tx*6;
  __syncthreads();

  for (int t = 0; t < 16; t++){
    int kv0 = kvbase + t*32;
    /* stage K tile [k][n] and V tile [n][c] */
    #pragma unroll
    for (int i = 0; i < 3; i++){
      int e = tid + i*256;
      int n = e & 31, kq = (e >> 5) * 4;
      float4 f = *reinterpret_cast<const float4*>(&MQ[(size_t)(kv0+n)*1152 + 384 + h*96 + kq]);
      Ksf[kq  ][n] = f.x;
      Ksf[kq+1][n] = f.y;
      Ksf[kq+2][n] = f.z;
      Ksf[kq+3][n] = f.w;
      int nv = e / 24, cq = (e - nv*24) * 4;
      float4 g = *reinterpret_cast<const float4*>(&MQ[(size_t)(kv0+nv)*1152 + 768 + h*96 + cq]);
      *reinterpret_cast<float4*>(&Vs[nv][cq]) = g;
    }
    __syncthreads();

    /* S = Q @ K^T (64x32), thread: rows ty*4..+3, kv cols tx*2..+1 */
    float s0[4] = {0,0,0,0}, s1[4] = {0,0,0,0};
    #pragma unroll 8
    for (int k = 0; k < 96; k++){
      float4 a4 = *reinterpret_cast<const float4*>(&Qs[k][ty*4]);
      float2 b2 = *reinterpret_cast<const float2*>(&Ksf[k][tx*2]);
      s0[0] += a4.x*b2.x; s1[0] += a4.x*b2.y;
      s0[1] += a4.y*b2.x; s1[1] += a4.y*b2.y;
      s0[2] += a4.z*b2.x; s1[2] += a4.z*b2.y;
      s0[3] += a4.w*b2.x; s1[3] += a4.w*b2.y;
    }
    /* online softmax per row */
    #pragma unroll
    for (int i=0;i<4;i++){
      float a = s0[i]*ISQ96, b = s1[i]*ISQ96;
      float rm = rgmax(fmaxf(a, b));
      float mn = fmaxf(m_i[i], rm);
      float alpha = expf(m_i[i] - mn);
      float p0 = expf(a - mn), p1 = expf(b - mn);
      float rs = rgsum(p0 + p1);
      l_i[i] = l_i[i]*alpha + rs;
      m_i[i] = mn;
      #pragma unroll
      for (int c=0;c<6;c++) acc[i][c] *= alpha;
      Ps[ty*4+i][tx*2  ] = p0;
      Ps[ty*4+i][tx*2+1] = p1;
    }
    __syncthreads();
    /* O += P @ V : thread rows ty*4..+3, cols c0..c0+5 */
    for (int kv = 0; kv < 32; kv++){
      float2 v01 = *reinterpret_cast<const float2*>(&Vs[kv][c0]);
      float2 v23 = *reinterpret_cast<const float2*>(&Vs[kv][c0+2]);
      float2 v45 = *reinterpret_cast<const float2*>(&Vs[kv][c0+4]);
      #pragma unroll
      for (int i=0;i<4;i++){
        float p = Ps[ty*4+i][kv];
        acc[i][0] += p*v01.x; acc[i][1] += p*v01.y;
        acc[i][2] += p*v23.x; acc[i][3] += p*v23.y;
        acc[i][4] += p*v45.x; acc[i][5] += p*v45.y;
      }
    }
    __syncthreads();
  }

  /* write unnormalized partials */
  size_t base = ((size_t)(h*nch + z)*nq + q0);
  #pragma unroll
  for (int i=0;i<4;i++){
    size_t row = base + ty*4 + i;
    #pragma unroll
    for (int c=0;c<6;c++) OP[row*96 + c0 + c] = acc[i][c];
    if (tx == 0){
      ML[row*2  ] = m_i[i];
      ML[row*2+1] = l_i[i];
    }
  }
}

__global__ void k_famerge(const float* __restrict__ OP, const float* __restrict__ ML,
                          float* __restrict__ AO_, int nq, int nch){
  int e = blockIdx.x*256 + threadIdx.x;
  int total = 4*nq*96;
  if (e >= total) return;
  int c = e % 96;
  int q = (e / 96) % nq;
  int h = e / (96*nq);
  float M = -3.0e38f;
  for (int z = 0; z < nch; z++)
    M = fmaxf(M, ML[((size_t)(h*nch+z)*nq + q)*2]);
  float L = 0.f, O = 0.f;
  for (int z = 0; z < nch; z++){
    size_t row = (size_t)(h*nch+z)*nq + q;
    float w = expf(ML[row*2] - M);
    L += ML[row*2+1]*w;
    O += OP[row*96 + c]*w;
  }
  AO_[(size_t)q*384 + h*96 + c] = O / L;
}

/* ---------------- conv1d as im2col + GEMM ---------------- */
/* imcol[p][ic*3+j] = in[p-1+j][ic] (0-pad); matches per-ic j-inner accumulation order */
__global__ void k_im2col(const float* __restrict__ in, float* __restrict__ imc){
  int e = blockIdx.x*256 + threadIdx.x;
  if (e >= 2048*1152) return;
  int p = e / 1152, k = e - p*1152;
  int ic = k / 3, j = k - ic*3;
  int gp = p - 1 + j;
  imc[e] = (gp >= 0 && gp < 2048) ? in[(size_t)gp*384 + ic] : 0.f;
}
/* WT[k][oc] = W[oc][k], K = 1152 */
__global__ void k_wtr(const float* __restrict__ W, float* __restrict__ WT, int OC){
  int e = blockIdx.x*256 + threadIdx.x;
  if (e >= OC*1152) return;
  int oc = e / 1152, k = e - oc*1152;
  WT[(size_t)k*OC + oc] = W[e];
}

/* ---------------- edge attention ---------------- */

__global__ __launch_bounds__(256) void k_escore(
    const float* __restrict__ KQV_, const float* __restrict__ KE_,
    const int* __restrict__ edg, const int* __restrict__ esr, const int* __restrict__ erl,
    const float* __restrict__ prel_l, float* __restrict__ EA)
{
  int e = blockIdx.x*4 + (threadIdx.x>>6);
  if (e >= NEDGE) return;
  int lane = threadIdx.x & 63;
  int h = lane >> 4, j = lane & 15;
  int dg = edg[e], sr = esr[e], r = erl[e];
  const float* q  = KQV_ + (size_t)dg*1152 + 384 + h*96;
  const float* ke = KE_  + (size_t)sr*384 + h*96;
  float p = 0.f;
  #pragma unroll
  for (int t=0;t<6;t++){ int d = j + t*16; p += q[d]*ke[d]; }
  p += __shfl_xor(p, 1, 64);
  p += __shfl_xor(p, 2, 64);
  p += __shfl_xor(p, 4, 64);
  p += __shfl_xor(p, 8, 64);
  if (j == 0) EA[(size_t)e*4 + h] = p * prel_l[r*4+h] * ISQ96;
}

__global__ void k_segmax(const float* __restrict__ EA, const int* __restrict__ edg,
                         unsigned* __restrict__ EMX){
  int i = blockIdx.x*256 + threadIdx.x;
  if (i >= NEDGE*4) return;
  int e = i >> 2, h = i & 3;
  atomicMax(&EMX[edg[e]*4 + h], encf(EA[i]));
}

__global__ void k_expsum(float* __restrict__ EA, const int* __restrict__ edg,
                         const unsigned* __restrict__ EMX, float* __restrict__ EDEN){
  int i = blockIdx.x*256 + threadIdx.x;
  if (i >= NEDGE*4) return;
  int e = i >> 2, h = i & 3;
  int dg = edg[e];
  float m = decf(EMX[dg*4 + h]);
  float ex = expf(EA[i] - m);
  EA[i] = ex;
  atomicAdd(&EDEN[dg*4 + h], ex);
}

__global__ __launch_bounds__(128) void k_agg(
    const float* __restrict__ EA, const float* __restrict__ VE_,
    const float* __restrict__ EDEN, const int* __restrict__ csr,
    const int* __restrict__ off, const int* __restrict__ esr, float* __restrict__ AGG)
{
  int node = blockIdx.x, tid = threadIdx.x;
  int b = off[node], e1 = off[node+1];
  int d0 = tid, d1 = tid+128, d2 = tid+256;
  int h0 = d0/96, h1 = d1/96, h2 = d2/96;
  float a0=0.f, a1=0.f, a2=0.f;
  if (e1 > b){
    float i0 = 1.0f/EDEN[node*4+h0];
    float i1 = 1.0f/EDEN[node*4+h1];
    float i2 = 1.0f/EDEN[node*4+h2];
    for (int p=b; p<e1; p++){
      int e = csr[p];
      const float* ve = VE_ + (size_t)esr[e]*384;
      const float* ea = EA + (size_t)e*4;
      a0 += ea[h0]*i0*ve[d0];
      a1 += ea[h1]*i1*ve[d1];
      a2 += ea[h2]*i2*ve[d2];
    }
  }
  AGG[(size_t)node*384 + d0] = a0;
  AGG[(size_t)node*384 + d1] = a1;
  AGG[(size_t)node*384 + d2] = a2;
}

/* ---------------- row-wise norm kernels ---------------- */

__global__ __launch_bounds__(128) void k_gateln(
    const float* __restrict__ O, float* __restrict__ X,
    const float* __restrict__ skip_l, const float* __restrict__ lng, const float* __restrict__ lnb)
{
  __shared__ float red[2];
  int row = blockIdx.x, tid = threadIdx.x;
  int t = row_type(row);
  float gt = sigm(skip_l[t]);
  const float* o = O + (size_t)row*384;
  float* x = X + (size_t)row*384;
  float v0 = gelu_f(gt*o[tid]     + (1.f-gt)*x[tid]);
  float v1 = gelu_f(gt*o[tid+128] + (1.f-gt)*x[tid+128]);
  float v2 = gelu_f(gt*o[tid+256] + (1.f-gt)*x[tid+256]);
  int lane = tid & 63, wid = tid >> 6;
  float s = wsum64(v0+v1+v2);
  if (lane==0) red[wid] = s;
  __syncthreads();
  float mean = (red[0]+red[1]) * (1.0f/384.0f);
  __syncthreads();
  float d0=v0-mean, d1=v1-mean, d2=v2-mean;
  float q = wsum64(d0*d0+d1*d1+d2*d2);
  if (lane==0) red[wid] = q;
  __syncthreads();
  float var = (red[0]+red[1]) * (1.0f/384.0f);
  float rs = 1.0f/sqrtf(var + 1e-5f);
  const float* g = lng + (size_t)t*384;
  const float* b = lnb + (size_t)t*384;
  x[tid]     = d0*rs*g[tid]     + b[tid];
  x[tid+128] = d1*rs*g[tid+128] + b[tid+128];
  x[tid+256] = d2*rs*g[tid+256] + b[tid+256];
}

__global__ __launch_bounds__(128) void k_lnrow(
    const float* __restrict__ X, float* __restrict__ Y,
    const float* __restrict__ g, const float* __restrict__ b, int act)
{
  __shared__ float red[2];
  int row = blockIdx.x, tid = threadIdx.x;
  const float* x = X + (size_t)row*384;
  float* y = Y + (size_t)row*384;
  float v0 = x[tid], v1 = x[tid+128], v2 = x[tid+256];
  int lane = tid & 63, wid = tid >> 6;
  float s = wsum64(v0+v1+v2);
  if (lane==0) red[wid] = s;
  __syncthreads();
  float mean = (red[0]+red[1]) * (1.0f/384.0f);
  __syncthreads();
  float d0=v0-mean, d1=v1-mean, d2=v2-mean;
  float q = wsum64(d0*d0+d1*d1+d2*d2);
  if (lane==0) red[wid] = q;
  __syncthreads();
  float var = (red[0]+red[1]) * (1.0f/384.0f);
  float rs = 1.0f/sqrtf(var + 1e-5f);
  float u0 = d0*rs*g[tid]     + b[tid];
  float u1 = d1*rs*g[tid+128] + b[tid+128];
  float u2 = d2*rs*g[tid+256] + b[tid+256];
  if (act==1){ u0=fmaxf(u0,0.f); u1=fmaxf(u1,0.f); u2=fmaxf(u2,0.f); }
  else       { u0=gelu_f(u0); u1=gelu_f(u1); u2=gelu_f(u2); }
  y[tid] = u0; y[tid+128] = u1; y[tid+256] = u2;
}

/* ---------------- reductions / misc ---------------- */

__global__ __launch_bounds__(256) void k_sumsq(const float* __restrict__ x, int n, float* out){
  __shared__ float red[4];
  float s = 0.f;
  for (int i = blockIdx.x*256 + threadIdx.x; i < n; i += gridDim.x*256){ float v=x[i]; s += v*v; }
  s = wsum64(s);
  int lane = threadIdx.x & 63, wid = threadIdx.x >> 6;
  if (lane==0) red[wid] = s;
  __syncthreads();
  if (threadIdx.x==0) atomicAdd(out, red[0]+red[1]+red[2]+red[3]);
}

__global__ void k_colsum(const float* __restrict__ A, int R, int C, float scale,
                         float* __restrict__ out){
  int col = blockIdx.x*256 + threadIdx.x;
  if (col >= C) return;
  int nchunk = gridDim.y;
  int chunk = (R + nchunk - 1)/nchunk;
  int r0 = blockIdx.y*chunk, r1 = min(R, r0+chunk);
  float s = 0.f;
  for (int r=r0; r<r1; r++) s += A[(size_t)r*C + col];
  atomicAdd(&out[col], s*scale);
}

__global__ __launch_bounds__(256) void k_dnm(const float* __restrict__ QB,
    const float* __restrict__ KSUM, const float* __restrict__ sqsk, float* __restrict__ DNM){
  int wv = blockIdx.x*4 + (threadIdx.x>>6);
  int n = wv >> 2, h = wv & 3;
  int lane = threadIdx.x & 63;
  const float* q = QB + (size_t)n*1536 + h*384;
  const float* ks = KSUM + h*384;
  float p = 0.f;
  #pragma unroll
  for (int d=lane; d<384; d+=64) p += q[d]*ks[d];
  p = wsum64(p);
  if (lane==0) DNM[n*4+h] = p * (1.0f/sqrtf(sqsk[0]*sqsk[1])) + 2048.0f;
}

__global__ void k_zcomb(const float* __restrict__ ZN, const float* __restrict__ VB_,
                        const float* __restrict__ DNM_, const float* __restrict__ sqsk,
                        float* __restrict__ XG_,
                        const float* __restrict__ bng, const float* __restrict__ bnb){
  int i = blockIdx.x*256 + threadIdx.x;
  if (i >= 2048*384) return;
  int n = i / 384, c = i - n*384;
  float inv_s = 1.0f/sqrtf(sqsk[0]*sqsk[1]);
  float zm = 0.f;
  #pragma unroll
  for (int h=0;h<4;h++){
    float num = ZN[(size_t)n*1536 + h*384 + c]*inv_s + 2048.0f*VB_[(size_t)n*1536 + h*384 + c];
    zm += num / DNM_[n*4+h];
  }
  zm *= 0.25f;
  float y = 0.5f*zm + 0.5f*XG_[i];
  y = y * (bng[c] * BNCONST) + bnb[c];
  XG_[i] = fmaxf(y, 0.f);
}

/* ---------------- parallel small GEMV: partials + finalize ---------------- */

__global__ __launch_bounds__(256) void k_gemv_ks(
    const float* __restrict__ in, int K, const float* __restrict__ W, int ldw,
    float* __restrict__ tmp, int N)
{
  int c = blockIdx.x*64 + (threadIdx.x & 63);
  int w = threadIdx.x >> 6;
  int kch = blockIdx.y, nk = gridDim.y;
  int k0 = (int)(((long long)K * kch) / nk);
  int k1 = (int)(((long long)K * (kch+1)) / nk);
  float s = 0.f;
  if (c < N){
    for (int k = k0 + w; k < k1; k += 4)
      s += in[k] * W[(size_t)k*ldw + c];
  }
  __shared__ float red[4][64];
  red[w][threadIdx.x & 63] = s;
  __syncthreads();
  if (w == 0 && c < N){
    int l = threadIdx.x & 63;
    tmp[(size_t)kch*N + c] = red[0][l] + red[1][l] + red[2][l] + red[3][l];
  }
}

__global__ void k_gemv_fin(const float* __restrict__ tmp, int nk,
                           const float* __restrict__ b, float* __restrict__ out, int N, int act){
  int c = blockIdx.x*256 + threadIdx.x;
  if (c >= N) return;
  float v = 0.f;
  for (int i = 0; i < nk; i++) v += tmp[(size_t)i*N + c];
  v += b[c];
  if (act==1) v = fmaxf(v, 0.f);
  out[c] = v;
}

__global__ __launch_bounds__(256) void k_rowdot(const float* __restrict__ A, int lda, int K,
    const float* __restrict__ w, const float* __restrict__ b, float* __restrict__ out, int M){
  int r = blockIdx.x*4 + (threadIdx.x>>6);
  if (r >= M) return;
  int lane = threadIdx.x & 63;
  const float* a = A + (size_t)r*lda;
  float p = 0.f;
  for (int k = lane; k < K; k += 64) p += a[k]*w[k];
  p = wsum64(p);
  if (lane==0) out[r] = sigm(p + b[0]);
}

__global__ __launch_bounds__(64) void k_final(const float* __restrict__ z2,
    const float* __restrict__ w, const float* __restrict__ b, float* __restrict__ out){
  int lane = threadIdx.x;
  float p = 0.f;
  for (int k = lane; k < 192; k += 64) p += z2[k]*w[k];
  p = wsum64(p);
  if (lane==0){
    float l = p + b[0];
    out[0] = l;
    out[1] = sigm(l);
  }
}

/* ================================================================ */

extern "C" void kernel_launch(void* const* d_in, const int* in_sizes, int n_in,
                              void* d_out, int out_size, void* d_ws, size_t ws_size,
                              hipStream_t stream)
{
  const float* xin[5] = {(const float*)d_in[0], (const float*)d_in[1], (const float*)d_in[2],
                         (const float*)d_in[3], (const float*)d_in[4]};
  const float* Wkqv=(const float*)d_in[5];  const float* bkqv=(const float*)d_in[6];
  const float* Wout=(const float*)d_in[7];  const float* bout=(const float*)d_in[8];
  const float* krel=(const float*)d_in[9];  const float* vrel=(const float*)d_in[10];
  const float* prel=(const float*)d_in[11]; const float* skp =(const float*)d_in[12];
  const float* lng =(const float*)d_in[13]; const float* lnb =(const float*)d_in[14];
  const float* sp_W=(const float*)d_in[15]; const float* sp_b=(const float*)d_in[16];
  const float* sp_lng=(const float*)d_in[17]; const float* sp_lnb=(const float*)d_in[18];
  const float* fc0_W=(const float*)d_in[19]; const float* fc0_b=(const float*)d_in[20];
  const float* bn_g=(const float*)d_in[21]; const float* bn_b=(const float*)d_in[22];
  const float* tq_W=(const float*)d_in[23]; const float* tq_b=(const float*)d_in[24];
  const float* tk_W=(const float*)d_in[25]; const float* tk_b=(const float*)d_in[26];
  const float* tv_W=(const float*)d_in[27]; const float* tv_b=(const float*)d_in[28];
  const float* mWqkv=(const float*)d_in[29]; const float* mbqkv=(const float*)d_in[30];
  const float* mWo=(const float*)d_in[31];  const float* mbo=(const float*)d_in[32];
  const float* c1W=(const float*)d_in[33];  const float* c1b=(const float*)d_in[34];
  const float* c2W=(const float*)d_in[35];  const float* c2b=(const float*)d_in[36];
  const float* opW=(const float*)d_in[37];  const float* opb=(const float*)d_in[38];
  const float* as1W=(const float*)d_in[39]; const float* as1b=(const float*)d_in[40];
  const float* as2W=(const float*)d_in[41]; const float* as2b=(const float*)d_in[42];
  const float* sc1W=(const float*)d_in[43]; const float* sc1b=(const float*)d_in[44];
  const float* sc2W=(const float*)d_in[45]; const float* sc2b=(const float*)d_in[46];
  const float* cl1W=(const float*)d_in[47]; const float* cl1b=(const float*)d_in[48];
  const float* cllng=(const float*)d_in[49]; const float* cllnb=(const float*)d_in[50];
  const float* cl2W=(const float*)d_in[51]; const float* cl2b=(const float*)d_in[52];
  const float* cl3W=(const float*)d_in[53]; const float* cl3b=(const float*)d_in[54];
  const float* tpW=(const float*)d_in[55];  const float* tpb=(const float*)d_in[56];
  const int* e_src=(const int*)d_in[57];  const int* e_dst=(const int*)d_in[58];
  float* out = (float*)d_out;

  /* workspace arena */
  char* ws = (char*)d_ws;
  size_t off_b = 0;
  auto alloc = [&](size_t bytes)->char*{
    char* r = ws + off_b;
    off_b = (off_b + bytes + 255) & ~(size_t)255;
    return r;
  };
  float* X    = (float*)alloc((size_t)8192*384*4);
  float* KQV  = (float*)alloc((size_t)8192*1152*4);
  float* KE   = (float*)alloc((size_t)14336*384*4);
  float* VE   = (float*)alloc((size_t)14336*384*4);
  float* AGG  = (float*)alloc((size_t)8192*384*4);
  float* EA   = (float*)alloc((size_t)NEDGE*4*4);
  int* edg    = (int*)alloc((size_t)NEDGE*4);
  int* esr    = (int*)alloc((size_t)NEDGE*4);
  int* erl    = (int*)alloc((size_t)NEDGE*4);
  int* csr    = (int*)alloc((size_t)NEDGE*4);
  int* cnt    = (int*)alloc(8192*4);
  int* cnt2   = (int*)alloc(8192*4);
  int* coff   = (int*)alloc(8193*4);
  unsigned* EMX = (unsigned*)alloc(8192*4*4);
  float* EDEN = (float*)alloc(8192*4*4);
  float* SM   = (float*)alloc(65536);
  float* GT   = (float*)alloc(20*384*4);
  if (off_b > ws_size) return;

  float* SQSK = SM;
  float* TRAJSUM = SM + 8;
  float* DECAYSUM = SM + 392;
  float* TEMB = SM + 600;
  float* AIPOOL = SM + 984;
  float* BCTXV = SM + 1368;
  float* SDELT = SM + 1752;
  float* SDIN = SM + 2048;
  float* T1   = SM + 2816;
  float* Z1   = SM + 3200;
  float* Zb   = SM + 3584;
  float* Z2   = SM + 3968;
  float* KSUM = SM + 4224;
  float* DNM  = SM + 6144;

  float* QB = KQV;
  float* KB = KQV + (size_t)2048*1536;
  float* VB = KQV + (size_t)2*2048*1536;
  float* MQKV = KQV;
  float* AO = KQV + (size_t)2*2048*1536;
  float* ZNUM = KE;
  float* OWT = KE;
  float* OPART = KE;                       /* flash partials: <= 4*4*2048*96 */
  float* MLBUF = KE + (size_t)3200000;     /* <= 65536 floats */
  float* IMC = KE;                         /* conv im2col 2048x1152 */
  float* WT  = KE + (size_t)2400000;       /* conv weight^T <= 1152*384 */
  float* HS = VE;
  float* XG = VE + (size_t)2048*384;
  float* HM = VE + (size_t)2*2048*384;
  float* C1O = VE + (size_t)3*2048*384;
  float* TRAJ = VE + (size_t)4*2048*384;
  float* AICTX = VE + (size_t)5*2048*384;
  float* C2O = VE + (size_t)6*2048*384;
  float* TMPA = AGG;
  float* CB = AGG;
  float* PT = AGG + (size_t)2048*768;
  float* KVS = AGG + (size_t)2048*1152;

  dim3 B256(256);
  auto gemm = [&](const float* A, int lda, const float* Bw, int ldb, const float* bias,
                  const float* cs, const float* csh, float kmul,
                  float* C, int ldc, int M, int N, int K, int act, int agelu){
    dim3 g((N+63)/64, (M+63)/64);
    gemm_f<<<g, B256, 0, stream>>>(A, lda, Bw, ldb, bias, cs, csh, kmul, C, ldc, M, N, K, act, agelu);
  };
  auto gemv = [&](const float* in, int K, const float* W, int ldw, const float* b,
                  float* o, int N, int act){
    int nk = (K + 79) / 80; if (nk > 20) nk = 20; if (nk < 1) nk = 1;
    k_gemv_ks<<<dim3((N+63)/64, nk), B256, 0, stream>>>(in, K, W, ldw, GT, N);
    k_gemv_fin<<<dim3((N+255)/256), B256, 0, stream>>>(GT, nk, b, o, N, act);
  };

  /* ---- edge CSR ---- */
  hipMemsetAsync(cnt, 0, 8192*4, stream);
  hipMemsetAsync(cnt2, 0, 8192*4, stream);
  k_edge_pre<<<dim3(NEDGE/256), B256, 0, stream>>>(e_src, e_dst, edg, esr, erl, cnt);
  k_scan<<<dim3(1), dim3(1024), 0, stream>>>(cnt, coff);
  k_scatter<<<dim3(NEDGE/256), B256, 0, stream>>>(edg, coff, cnt2, csr);

  /* ---- inputs -> X ---- */
  for (int t=0;t<5;t++)
    hipMemcpyAsync(X + (size_t)h_OFFS[t]*384, xin[t], (size_t)h_NT[t]*384*4,
                   hipMemcpyDeviceToDevice, stream);

  /* ---- HGT layers ---- */
  for (int l=0;l<2;l++){
    /* combined 5-type KQV projection: one 64x128-tile launch, per-tile type select */
    gemm128<<<dim3(9, 128), B256, 0, stream>>>(
        X, 384, 0,
        Wkqv + (size_t)l*5*442368, 1152, 442368,
        bkqv + (size_t)l*5*1152, 1152,
        KQV, 1152, 0, 8192, 1152, 384, 0, 0, 1 /*tsel*/,
        nullptr, nullptr, nullptr, nullptr);
    gemm_rel<<<dim3(2,32,64), B256, 0, stream>>>(
        KQV, krel + (size_t)l*294912, vrel + (size_t)l*294912, KE, VE);
    k_escore<<<dim3(NEDGE/4), B256, 0, stream>>>(KQV, KE, edg, esr, erl, prel + (size_t)l*32, EA);
    hipMemsetAsync(EMX, 0, 8192*4*4, stream);
    hipMemsetAsync(EDEN, 0, 8192*4*4, stream);
    k_segmax<<<dim3(NEDGE*4/256), B256, 0, stream>>>(EA, edg, EMX);
    k_expsum<<<dim3(NEDGE*4/256), B256, 0, stream>>>(EA, edg, EMX, EDEN);
    k_agg<<<dim3(NTOT), dim3(128), 0, stream>>>(EA, VE, EDEN, csr, coff, esr, AGG);
    /* combined 5-type Wout projection (gelu on A) */
    gemm128<<<dim3(3, 128), B256, 0, stream>>>(
        AGG, 384, 0,
        Wout + (size_t)l*5*147456, 384, 147456,
        bout + (size_t)l*5*384, 384,
        OWT, 384, 0, 8192, 384, 384, 0, 1 /*agelu*/, 1 /*tsel*/,
        nullptr, nullptr, nullptr, nullptr);
    k_gateln<<<dim3(NTOT), dim3(128), 0, stream>>>(OWT, X, skp + l*5, lng, lnb);
  }

  const float* user_h   = X;
  const float* ai_h     = X + (size_t)2048*384;
  const float* stance_h = X + (size_t)4096*384;
  const float* belief_h = X + (size_t)7168*384;

  /* ---- hs, xg ---- */
  gemm(stance_h, 384, sp_W, 384, sp_b, nullptr, nullptr, 1.f, TMPA, 384, 2048, 384, 384, 0, 0);
  k_lnrow<<<dim3(2048), dim3(128), 0, stream>>>(TMPA, HS, sp_lng, sp_lnb, 0 /*gelu*/);
  gemm(HS, 384, fc0_W, 384, fc0_b, bn_g, bn_b, BNCONST, XG, 384, 2048, 384, 384, 1 /*relu*/, 0);

  /* ---- linear-attention blocks ---- */
  for (int i=0;i<2;i++){
    /* q/k/v projections batched into one launch: z selects weight/bias pointer,
       C strided (QB,KB,VB contiguous in arena) */
    gemm128<<<dim3(12,32,3), B256, 0, stream>>>(
        XG, 384, 0,
        tq_W + (size_t)i*589824, 1536, 0,
        tq_b + (size_t)i*1536, 0,
        QB, 1536, 2048*1536,
        2048, 1536, 384, 0, 0, 0,
        tk_W + (size_t)i*589824, tv_W + (size_t)i*589824,
        tk_b + (size_t)i*1536, tv_b + (size_t)i*1536);
    hipMemsetAsync(SQSK, 0, 8, stream);
    k_sumsq<<<dim3(512), B256, 0, stream>>>(QB, 2048*1536, SQSK);
    k_sumsq<<<dim3(512), B256, 0, stream>>>(KB, 2048*1536, SQSK+1);
    hipMemsetAsync(KSUM, 0, 1536*4, stream);
    k_colsum<<<dim3(6,8), B256, 0, stream>>>(KB, 2048, 1536, 1.0f, KSUM);
    k_dnm<<<dim3(2048), B256, 0, stream>>>(QB, KSUM, SQSK, DNM);
    hipMemsetAsync(KVS, 0, (size_t)4*147456*4, stream);
    gemm_atb_ks<<<dim3(6,6,32), B256, 0, stream>>>(KB, 1536, VB, 1536, KVS, 384,
        384, 384, 2048, 384, 384, 147456, 8);
    /* 4-head ZNUM batched via grid.z */
    gemm128<<<dim3(3,32,4), B256, 0, stream>>>(
        QB, 1536, 384, KVS, 384, 147456,
        nullptr, 0, ZNUM, 1536, 384, 2048, 384, 384, 0, 0, 0,
        nullptr, nullptr, nullptr, nullptr);
    k_zcomb<<<dim3(3072), B256, 0, stream>>>(ZNUM, VB, DNM, SQSK, XG,
        bn_g + (size_t)(i+1)*384, bn_b + (size_t)(i+1)*384);
  }

  /* ---- h_mixed ---- */
  k_mix<<<dim3(3072), B256, 0, stream>>>(HS, XG, HM, 2048*384, 0.7f, 0.3f);

  /* ---- MHA helper (flash) ---- */
  auto run_mha = [&](const float* qin, int nq, const float* kvin, int nkv, int mi, float* OUT){
    const float* Wq = mWqkv + (size_t)mi*442368;
    const float* bq = mbqkv + (size_t)mi*1152;
    gemm(qin, 384, Wq, 1152, bq, nullptr, nullptr, 1.f, MQKV, 1152, nq, 384, 384, 0, 0);
    gemm(kvin, 384, Wq + 384, 1152, bq + 384, nullptr, nullptr, 1.f, MQKV + 384, 1152, nkv, 768, 384, 0, 0);
    int nch = nkv / 512;
    fa_kernel<<<dim3(nq/64, 4, nch), B256, 0, stream>>>(MQKV, nq, OPART, MLBUF);
    k_famerge<<<dim3((4*nq*96 + 255)/256), B256, 0, stream>>>(OPART, MLBUF, AO, nq, nch);
    gemm(AO, 384, mWo + (size_t)mi*147456, 384, mbo + (size_t)mi*384,
         nullptr, nullptr, 1.f, OUT, 384, nq, 384, 384, 0, 0);
  };

  /* ---- traj ---- */
  run_mha(HM, 2048, HM, 2048, 1, TRAJ);
  hipMemsetAsync(TRAJSUM, 0, 576*4, stream);
  k_colsum<<<dim3(2,8), B256, 0, stream>>>(TRAJ, 2048, 384, 1.0f/2048.0f, TRAJSUM);

  /* ---- conv path (im2col + GEMM, gelu epilogue) ---- */
  k_im2col<<<dim3(2048*1152/256), B256, 0, stream>>>(HM, IMC);
  k_wtr<<<dim3((384*1152+255)/256), B256, 0, stream>>>(c1W, WT, 384);
  gemm(IMC, 1152, WT, 384, c1b, nullptr, nullptr, 1.f, C1O, 384, 2048, 384, 1152, 2 /*gelu*/, 0);
  k_im2col<<<dim3(2048*1152/256), B256, 0, stream>>>(C1O, IMC);
  k_wtr<<<dim3((192*1152+255)/256), B256, 0, stream>>>(c2W, WT, 192);
  gemm(IMC, 1152, WT, 192, c2b, nullptr, nullptr, 1.f, C2O, 192, 2048, 192, 1152, 2 /*gelu*/, 0);
  k_colsum<<<dim3(1,8), B256, 0, stream>>>(C2O, 2048, 192, 1.0f/2048.0f, DECAYSUM);

  /* ---- traj_emb ---- */
  gemv(TRAJSUM, 576, opW, 384, opb, TEMB, 384, 0);

  /* ---- ai_ctx ---- */
  run_mha(ai_h, 2048, user_h, 2048, 0, AICTX);
  hipMemsetAsync(AIPOOL, 0, 384*4, stream);
  k_colsum<<<dim3(2,8), B256, 0, stream>>>(AICTX, 2048, 384, 1.0f/2048.0f, AIPOOL);

  /* ---- pscores ---- */
  k_comb<<<dim3(6144), B256, 0, stream>>>(ai_h, user_h, CB);
  gemm(CB, 768, as1W, 384, as1b, nullptr, nullptr, 1.f, PT, 384, 2048, 384, 768, 1, 0);
  k_rowdot<<<dim3(512), B256, 0, stream>>>(PT, 384, 384, as2W, as2b, out + 2 + 2048, 2048);

  /* ---- bctx ---- */
  run_mha(ai_h, 2048, belief_h, 1024, 2, TRAJ);
  hipMemsetAsync(BCTXV, 0, 384*4, stream);
  k_colsum<<<dim3(2,8), B256, 0, stream>>>(TRAJ, 2048, 384, 1.0f/2048.0f, BCTXV);

  /* ---- stance delta ---- */
  hipMemcpyAsync(SDIN, stance_h, 384*4, hipMemcpyDeviceToDevice, stream);
  hipMemcpyAsync(SDIN + 384, stance_h + (size_t)2047*384, 384*4, hipMemcpyDeviceToDevice, stream);
  gemv(SDIN, 768, sc1W, 384, sc1b, T1, 384, 1);
  gemv(T1, 384, sc2W, 192, sc2b, SDELT, 192, 0);

  /* ---- classifier ---- */
  gemv(TEMB, 1344, cl1W, 384, cl1b, Z1, 384, 0);
  k_lnrow<<<dim3(1), dim3(128), 0, stream>>>(Z1, Zb, cllng, cllnb, 1 /*relu*/);
  gemv(Zb, 384, cl2W, 192, cl2b, Z2, 192, 1);
  k_final<<<dim3(1), dim3(64), 0, stream>>>(Z2, cl3W, cl3b, out);

  /* ---- per_turn ---- */
  k_rowdot<<<dim3(512), B256, 0, stream>>>(AICTX, 384, 384, tpW, tpb, out + 2, 2048);
}